// Round 7
// baseline (505.693 us; speedup 1.0000x reference)
//
#include <hip/hip_runtime.h>
#include <hip/hip_bf16.h>

#define N_NODES 50000
#define N_EDGES 1600000
#define HEADS 8
#define NBK 196   // buckets: dst>>8
#define NBLK 196  // edge tiles: 196*8192 >= 1.6M
#define EPB 8192  // edges per bucket-build block
#define QSTRIDE 1600000  // 50000 * 32 elements per channel-quarter

typedef unsigned short u16;
typedef unsigned char u8;
typedef unsigned int u32;
typedef __attribute__((ext_vector_type(8))) short bf16x8;
typedef __attribute__((ext_vector_type(4))) float f32x4;

__device__ __forceinline__ float bf2f(u16 u) {
  union { u32 i; float f; } v; v.i = ((u32)u) << 16; return v.f;
}
__device__ __forceinline__ float bflo(u32 p) {
  union { u32 i; float f; } v; v.i = p << 16; return v.f;
}
__device__ __forceinline__ float bfhi(u32 p) {
  union { u32 i; float f; } v; v.i = p & 0xffff0000u; return v.f;
}
__device__ __forceinline__ u16 f2bf(float f) {
  union { float f; u32 i; } v; v.f = f;
  u32 r = v.i + 0x7fff + ((v.i >> 16) & 1);  // RNE
  return (u16)(r >> 16);
}
__device__ __forceinline__ u32 pack2(float a, float b) {
  return (u32)f2bf(a) | ((u32)f2bf(b) << 16);
}
__device__ __forceinline__ int rfl(int x) { return __builtin_amdgcn_readfirstlane(x); }

// ---------------- dtype auto-detection ----------------
__global__ void k_detect(const u16* __restrict__ x, const u32* __restrict__ ei,
                         int* __restrict__ flags) {
  __shared__ int cbig, cnz;
  if (threadIdx.x == 0) { cbig = 0; cnz = 0; }
  __syncthreads();
  int lb = 0, ln = 0;
  for (int i = threadIdx.x; i < 4096; i += 256) {
    int ex = (x[i] >> 7) & 0xff;
    lb += (ex >= 140);
    if (i < 2048) ln += (ei[2 * i + 1] != 0);
  }
  atomicAdd(&cbig, lb); atomicAdd(&cnz, ln);
  __syncthreads();
  if (threadIdx.x == 0) {
    flags[0] = (cbig > 16) ? 1 : 0;   // 1: floats are fp32
    flags[1] = (cnz == 0) ? 1 : 0;    // 1: edge_index is int64
  }
}

// ---------------- converter: vectors -> fp32, W1/W2 -> transposed bf16 -------
__global__ void k_convsmall(const void* a1s, const void* a1d, const void* b1,
                            const void* gam, const void* bet, const void* a2s,
                            const void* a2d, const void* b2, const void* W1,
                            const void* W2, float* __restrict__ smallf,
                            u16* __restrict__ w1t, u16* __restrict__ w2t,
                            const int* __restrict__ flags) {
  int i = blockIdx.x * 256 + threadIdx.x;
  if (i >= 25408) return;
  bool f32 = flags[0] != 0;
  auto ld = [&](const void* p, int off) -> float {
    return f32 ? ((const float*)p)[off] : bf2f(((const u16*)p)[off]);
  };
  if (i >= 17216) {            // W2T[n][k], n<64, k<128  <- W2[k*64+n]
    int j = i - 17216, n = j >> 7, k = j & 127;
    w2t[j] = f2bf(ld(W2, k * 64 + n));
  } else if (i >= 832) {       // W1T[n][k], n<128, k<128 <- W1[k*128+n]
    int j = i - 832, n = j >> 7, k = j & 127;
    w1t[j] = f2bf(ld(W1, k * 128 + n));
  } else {
    const void* src; int off;
    if (i >= 768)      { src = b2;  off = i - 768; }
    else if (i >= 704) { src = a2d; off = i - 704; }
    else if (i >= 640) { src = a2s; off = i - 640; }
    else if (i >= 512) { src = bet; off = i - 512; }
    else if (i >= 384) { src = gam; off = i - 384; }
    else if (i >= 256) { src = b1;  off = i - 256; }
    else if (i >= 128) { src = a1d; off = i - 128; }
    else               { src = a1s; off = i; }
    smallf[i] = ld(src, off);
  }
}

// ---------------- CSR build (atomic-free two-level counting sort) ----------
__global__ __launch_bounds__(256) void k_hist(const int* __restrict__ ei,
                                              int* __restrict__ H,
                                              int* __restrict__ totals,
                                              const int* __restrict__ flags) {
  __shared__ int hist[NBK];
  int t = threadIdx.x, blk = blockIdx.x;
  for (int i = t; i < NBK; i += 256) hist[i] = 0;
  __syncthreads();
  bool i64 = flags[1] != 0;
  int base = blk * EPB;
  for (int k = 0; k < 32; k++) {
    int e = base + k * 256 + t;
    if (e < N_EDGES) {
      int d = i64 ? ei[2 * (N_EDGES + e)] : ei[N_EDGES + e];
      atomicAdd(&hist[d >> 8], 1);
    }
  }
  __syncthreads();
  for (int i = t; i < NBK; i += 256) {
    H[i * NBLK + blk] = hist[i];
    atomicAdd(&totals[i], hist[i]);
  }
}

__global__ void k_scan_tot(const int* __restrict__ totals, int* __restrict__ bucketBase) {
  __shared__ int tmp[256];
  int t = threadIdx.x;
  int v = (t < NBK) ? totals[t] : 0;
  tmp[t] = v; __syncthreads();
  for (int o = 1; o < 256; o <<= 1) {
    int x = (t >= o) ? tmp[t - o] : 0; __syncthreads();
    tmp[t] += x; __syncthreads();
  }
  if (t < NBK) bucketBase[t] = tmp[t] - v;
  if (t == NBK - 1) bucketBase[NBK] = tmp[t];
}

__global__ void k_scan_blk(const int* __restrict__ H, const int* __restrict__ bucketBase,
                           int* __restrict__ P) {
  __shared__ int tmp[256];
  int t = threadIdx.x, b = blockIdx.x;
  int v = (t < NBLK) ? H[b * NBLK + t] : 0;
  tmp[t] = v; __syncthreads();
  for (int o = 1; o < 256; o <<= 1) {
    int x = (t >= o) ? tmp[t - o] : 0; __syncthreads();
    tmp[t] += x; __syncthreads();
  }
  if (t < NBLK) P[b * NBLK + t] = bucketBase[b] + tmp[t] - v;
}

// LDS counting sort per 8192-edge tile, coalesced global writes.
__global__ __launch_bounds__(256) void k_bucket(const int* __restrict__ ei,
                                                const int* __restrict__ P,
                                                u32* __restrict__ buf,
                                                const int* __restrict__ flags) {
  __shared__ u32 sv[EPB];
  __shared__ u16 rank[EPB];
  __shared__ u8  sk8[EPB];
  __shared__ int cnt[NBK], scn[NBK], tmp[256];
  int t = threadIdx.x, blk = blockIdx.x;
  int base = blk * EPB;
  int nE = N_EDGES - base; if (nE > EPB) nE = EPB;
  for (int i = t; i < NBK; i += 256) cnt[i] = 0;
  __syncthreads();
  bool i64 = flags[1] != 0;
  for (int k = 0; k < EPB / 256; k++) {
    int li = k * 256 + t, e = base + li;
    if (li < nE) {
      int d = i64 ? ei[2 * (N_EDGES + e)] : ei[N_EDGES + e];
      rank[li] = (u16)atomicAdd(&cnt[d >> 8], 1);
    }
  }
  __syncthreads();
  int v = (t < NBK) ? cnt[t] : 0;
  tmp[t] = v; __syncthreads();
  for (int o = 1; o < 256; o <<= 1) {
    int x = (t >= o) ? tmp[t - o] : 0; __syncthreads();
    tmp[t] += x; __syncthreads();
  }
  if (t < NBK) scn[t] = tmp[t] - v;
  __syncthreads();
  for (int k = 0; k < EPB / 256; k++) {
    int li = k * 256 + t, e = base + li;
    if (li < nE) {
      int s = i64 ? ei[2 * e] : ei[e];
      int d = i64 ? ei[2 * (N_EDGES + e)] : ei[N_EDGES + e];
      int key = d >> 8;
      int pos = scn[key] + rank[li];
      sv[pos] = ((u32)(d & 255) << 16) | (u32)s;
      sk8[pos] = (u8)key;
    }
  }
  __syncthreads();
  for (int i = t; i < nE; i += 256) {
    int b = sk8[i];
    buf[P[b * NBLK + blk] + (i - scn[b])] = sv[i];
  }
}

__global__ __launch_bounds__(256) void k_csr(const u32* __restrict__ buf,
                                             const int* __restrict__ bucketBase,
                                             int* __restrict__ row_start,
                                             int* __restrict__ deg,
                                             int* __restrict__ csr, int N) {
  __shared__ int cnt[256], scn[256], cur[256];
  int b = blockIdx.x, t = threadIdx.x;
  int lo = bucketBase[b], hi = bucketBase[b + 1];
  cnt[t] = 0; __syncthreads();
  for (int e = lo + t; e < hi; e += 256) atomicAdd(&cnt[(buf[e] >> 16) & 255], 1);
  __syncthreads();
  int v = cnt[t];
  scn[t] = v; __syncthreads();
  for (int o = 1; o < 256; o <<= 1) {
    int x = (t >= o) ? scn[t - o] : 0; __syncthreads();
    scn[t] += x; __syncthreads();
  }
  int excl = scn[t] - v;
  int node = b * 256 + t;
  if (node < N) { row_start[node] = lo + excl; deg[node] = v; }
  cur[t] = lo + excl;
  __syncthreads();
  for (int e = lo + t; e < hi; e += 256) {
    u32 p = buf[e];
    int pos = atomicAdd(&cur[(p >> 16) & 255], 1);
    csr[pos] = p & 0xffff;
  }
}

// ---------------- MFMA GEMM -> quarter-split bf16 C + fused alpha epilogues --
// C layout: C[(col>>5)*QSTRIDE + row*32 + (col&31)]  (channel-quarter split)
// ALPHA1 (layer1): per-head (=per-nt) dots vs a1s/a1d -> as_out/ad_out [row*8+nt]
// EPI (layer2): BN+ELU fused on A-load; alpha2 dots -> as_out/ad_out [row]
template <int NCOLS, bool EPI, bool ALPHA1, bool AFLAG>
__global__ __launch_bounds__(256) void k_gemm_mfma(const void* __restrict__ A,
                                                   const u16* __restrict__ BT,
                                                   const float* __restrict__ scale,
                                                   const float* __restrict__ shift,
                                                   const float* __restrict__ va,
                                                   const float* __restrict__ vb,
                                                   float* __restrict__ as_out,
                                                   float* __restrict__ ad_out,
                                                   u16* __restrict__ C, int M,
                                                   const int* __restrict__ flags) {
  constexpr int KP = 136;
  constexpr int NT = NCOLS / 16;
  __shared__ u16 As[64 * KP];
  __shared__ u16 Bs[NCOLS * KP];
  int t = threadIdx.x;
  int row0 = blockIdx.x * 64;
  bool af32 = AFLAG ? (flags[0] != 0) : false;

  for (int i = t; i < NCOLS * 16; i += 256) {
    int n = i >> 4, q = i & 15;
    *(uint4*)&Bs[n * KP + q * 8] = ((const uint4*)BT)[n * 16 + q];
  }
  for (int i = t; i < 64 * 32; i += 256) {
    int r = i >> 5, c4 = i & 31;
    int row = row0 + r;
    uint2 pk = make_uint2(0u, 0u);
    if (row < M) {
      if (EPI) {
        uint2 p = ((const uint2*)A)[(size_t)row * 32 + c4];
        int c = c4 * 4;
        float v0 = bflo(p.x), v1 = bfhi(p.x), v2 = bflo(p.y), v3 = bfhi(p.y);
        v0 = fmaf(v0, scale[c],     shift[c]);     v0 = v0 > 0.f ? v0 : __expf(v0) - 1.f;
        v1 = fmaf(v1, scale[c + 1], shift[c + 1]); v1 = v1 > 0.f ? v1 : __expf(v1) - 1.f;
        v2 = fmaf(v2, scale[c + 2], shift[c + 2]); v2 = v2 > 0.f ? v2 : __expf(v2) - 1.f;
        v3 = fmaf(v3, scale[c + 3], shift[c + 3]); v3 = v3 > 0.f ? v3 : __expf(v3) - 1.f;
        pk.x = pack2(v0, v1); pk.y = pack2(v2, v3);
      } else if (af32) {
        float4 v = ((const float4*)A)[(size_t)row * 32 + c4];
        pk.x = pack2(v.x, v.y); pk.y = pack2(v.z, v.w);
      } else {
        pk = ((const uint2*)A)[(size_t)row * 32 + c4];
      }
    }
    *(uint2*)&As[r * KP + c4 * 4] = pk;
  }
  __syncthreads();

  int lane = t & 63, w = t >> 6;
  int m = lane & 15, quad = lane >> 4;
  f32x4 acc[NT];
#pragma unroll
  for (int nt = 0; nt < NT; nt++) acc[nt] = (f32x4)(0.f);
  const u16* aBase = &As[(w * 16 + m) * KP + quad * 8];
  const u16* bBase = &Bs[m * KP + quad * 8];
#pragma unroll
  for (int ks = 0; ks < 4; ks++) {
    bf16x8 af = *(const bf16x8*)(aBase + ks * 32);
#pragma unroll
    for (int nt = 0; nt < NT; nt++) {
      bf16x8 bf = *(const bf16x8*)(bBase + nt * 16 * KP + ks * 32);
      acc[nt] = __builtin_amdgcn_mfma_f32_16x16x32_bf16(af, bf, acc[nt], 0, 0, 0);
    }
  }
  int orow0 = row0 + w * 16 + quad * 4;
#pragma unroll
  for (int nt = 0; nt < NT; nt++) {
    size_t base = (size_t)(nt >> 1) * QSTRIDE + ((nt & 1) * 16 + m);
#pragma unroll
    for (int r = 0; r < 4; r++) {
      int row = orow0 + r;
      if (row < M) C[base + (size_t)row * 32] = f2bf(acc[nt][r]);
    }
  }
  if (ALPHA1) {  // per-head dots: head == nt (16 ch/head)
    float pav[NT], pbv[NT];
#pragma unroll
    for (int nt = 0; nt < NT; nt++) { pav[nt] = va[nt * 16 + m]; pbv[nt] = vb[nt * 16 + m]; }
#pragma unroll
    for (int r = 0; r < 4; r++) {
      int row = orow0 + r;
#pragma unroll
      for (int nt = 0; nt < NT; nt++) {
        float vs = acc[nt][r] * pav[nt];
        float vd = acc[nt][r] * pbv[nt];
        vs += __shfl_xor(vs, 1); vd += __shfl_xor(vd, 1);
        vs += __shfl_xor(vs, 2); vd += __shfl_xor(vd, 2);
        vs += __shfl_xor(vs, 4); vd += __shfl_xor(vd, 4);
        vs += __shfl_xor(vs, 8); vd += __shfl_xor(vd, 8);
        if (row < M && m == 0) { as_out[row * 8 + nt] = vs; ad_out[row * 8 + nt] = vd; }
      }
    }
  }
  if (EPI) {  // fused alpha2
    float pav[NT], pbv[NT];
#pragma unroll
    for (int nt = 0; nt < NT; nt++) { pav[nt] = va[nt * 16 + m]; pbv[nt] = vb[nt * 16 + m]; }
#pragma unroll
    for (int r = 0; r < 4; r++) {
      float vs = 0.f, vd = 0.f;
#pragma unroll
      for (int nt = 0; nt < NT; nt++) {
        vs = fmaf(acc[nt][r], pav[nt], vs);
        vd = fmaf(acc[nt][r], pbv[nt], vd);
      }
      vs += __shfl_xor(vs, 1); vd += __shfl_xor(vd, 1);
      vs += __shfl_xor(vs, 2); vd += __shfl_xor(vd, 2);
      vs += __shfl_xor(vs, 4); vd += __shfl_xor(vd, 4);
      vs += __shfl_xor(vs, 8); vd += __shfl_xor(vd, 8);
      int row = orow0 + r;
      if (row < M && m == 0) { as_out[row] = vs; ad_out[row] = vd; }
    }
  }
}

// ---------------- aggregation layer 1: channel-quarter phases --------------
// grid = 4*12500; bq = quarter (channels bq*32..+31, heads bq*2, bq*2+1).
// lane: c = l&31 (channel in quarter), eh = l>>5 (edge parity).
// exp lanes 0..15: head2 = (l>>3)&1, slot = l&7.
__global__ __launch_bounds__(256) void k_agg1(const u16* __restrict__ h1r,
                                              const float* __restrict__ as_,
                                              const float* __restrict__ ad_,
                                              const int* __restrict__ csr,
                                              const int* __restrict__ row_start,
                                              const int* __restrict__ deg,
                                              const float* __restrict__ b1,
                                              u16* __restrict__ out, int N) {
  int bq = blockIdx.x / 12500;
  int nb = blockIdx.x - bq * 12500;
  int node = nb * 4 + (threadIdx.x >> 6);
  if (node >= N) return;
  int l = threadIdx.x & 63;
  int c = l & 31, eh = l >> 5;
  int h2sel = c >> 4;
  int node_u = rfl(node);
  int st = rfl(row_start[node_u]);
  int cnt = rfl(deg[node_u]);
  const int* cp = csr + st;
  const u16* hq = h1r + (size_t)bq * QSTRIDE;
  int q2 = bq * 2;
  int myh = (l >> 3) & 1;
  float ad = ad_[node_u * 8 + q2 + myh];
  float sp = 0.f, a = 0.f;
  int j = 0;
  for (; j + 8 <= cnt; j += 8) {
    int svi = cp[j + (l & 7)];                 // per-lane (16 exp lanes matter)
    float e = as_[svi * 8 + q2 + myh] + ad;
    e = fmaxf(e, 0.2f * e);
    float p = __expf(e);
    if (l < 16) sp += p;
#pragma unroll
    for (int k = 0; k < 4; k++) {
      int se = cp[j + 2 * k], so = cp[j + 2 * k + 1];  // uniform -> scalar
      int sk = eh ? so : se;
      float pk = __shfl(p, (h2sel << 3) | (2 * k + eh));
      a = fmaf(pk, bf2f(hq[(size_t)sk * 32 + c]), a);
    }
  }
  for (; j <= cnt; j++) {  // tail edges, then self-loop at j==cnt
    int s0 = (j < cnt) ? rfl(cp[j]) : node_u;
    float e = as_[s0 * 8 + q2 + myh] + ad;
    e = fmaxf(e, 0.2f * e);
    float p = __expf(e);
    if ((l & 55) == 0) sp += p;                // lanes 0, 8 only
    float pk = __shfl(p, h2sel << 3);
    if (eh == 0) a = fmaf(pk, bf2f(hq[(size_t)s0 * 32 + c]), a);
  }
  sp += __shfl_xor(sp, 1);
  sp += __shfl_xor(sp, 2);
  sp += __shfl_xor(sp, 4);
  float inv = 1.f / (__shfl(sp, h2sel << 3) + 1e-16f);
  a += __shfl_xor(a, 32);
  if (eh == 0) {
    int ch = bq * 32 + c;
    out[(size_t)node_u * 128 + ch] = f2bf(fmaf(a, inv, b1[ch]));
  }
}

// ---------------- batch norm ----------------
__global__ void k_bnstat(const u16* __restrict__ h, float* __restrict__ gsum,
                         float* __restrict__ gsq, int N) {
  __shared__ float ts[256], tq[256];
  int t = threadIdx.x, col = t & 127, rr = t >> 7;
  int row0 = blockIdx.x * 128;
  float s = 0.f, q = 0.f;
  for (int r = rr; r < 128; r += 2) {
    int row = row0 + r;
    if (row < N) {
      float v = bf2f(h[((size_t)row << 7) + col]);
      s += v; q = fmaf(v, v, q);
    }
  }
  ts[t] = s; tq[t] = q; __syncthreads();
  if (t < 128) {
    atomicAdd(&gsum[t], ts[t] + ts[t + 128]);
    atomicAdd(&gsq[t], tq[t] + tq[t + 128]);
  }
}

__global__ void k_bnfin(const float* __restrict__ gsum, const float* __restrict__ gsq,
                        const float* __restrict__ gamma, const float* __restrict__ beta,
                        float* __restrict__ scale, float* __restrict__ shift, int N) {
  int t = threadIdx.x;
  if (t >= 128) return;
  float mu = gsum[t] / (float)N;
  float var = fmaxf(gsq[t] / (float)N - mu * mu, 0.f);
  float s = gamma[t] * rsqrtf(var + 1e-5f);
  scale[t] = s;
  shift[t] = beta[t] - mu * s;
}

// ---------------- aggregation layer 2: 2 channel-quarter phases ------------
__global__ __launch_bounds__(256) void k_agg2(const u16* __restrict__ h2q,
                                              const float* __restrict__ as_,
                                              const float* __restrict__ ad_,
                                              const int* __restrict__ csr,
                                              const int* __restrict__ row_start,
                                              const int* __restrict__ deg,
                                              const float* __restrict__ b2,
                                              void* __restrict__ out,
                                              const int* __restrict__ flags, int N) {
  int bq = blockIdx.x / 12500;
  int nb = blockIdx.x - bq * 12500;
  int node = nb * 4 + (threadIdx.x >> 6);
  if (node >= N) return;
  int l = threadIdx.x & 63;
  int c = l & 31, eh = l >> 5;
  int node_u = rfl(node);
  int st = rfl(row_start[node_u]);
  int cnt = rfl(deg[node_u]);
  const int* cp = csr + st;
  const u16* hq = h2q + (size_t)bq * QSTRIDE;
  float ad = ad_[node_u];
  float sp = 0.f, a = 0.f;
  int j = 0;
  for (; j + 8 <= cnt; j += 8) {
    int svi = cp[j + (l & 7)];
    float e = as_[svi] + ad;
    e = fmaxf(e, 0.2f * e);
    float p = __expf(e);
    if (l < 8) sp += p;
#pragma unroll
    for (int k = 0; k < 4; k++) {
      int se = cp[j + 2 * k], so = cp[j + 2 * k + 1];
      int sk = eh ? so : se;
      float pk = __shfl(p, 2 * k + eh);
      a = fmaf(pk, bf2f(hq[(size_t)sk * 32 + c]), a);
    }
  }
  for (; j <= cnt; j++) {  // tail + self-loop
    int s0 = (j < cnt) ? rfl(cp[j]) : node_u;
    float e = as_[s0] + ad;
    e = fmaxf(e, 0.2f * e);
    float p = __expf(e);
    if (l == 0) sp += p;
    float pk = __shfl(p, 0);
    if (eh == 0) a = fmaf(pk, bf2f(hq[(size_t)s0 * 32 + c]), a);
  }
  sp += __shfl_xor(sp, 1);
  sp += __shfl_xor(sp, 2);
  sp += __shfl_xor(sp, 4);
  float inv = 1.f / (__shfl(sp, 0) + 1e-16f);
  a += __shfl_xor(a, 32);
  if (eh == 0) {
    int ch = bq * 32 + c;
    float r = fmaf(a, inv, b2[ch]);
    size_t idx = (size_t)node_u * 64 + ch;
    if (flags[0]) ((float*)out)[idx] = r;
    else          ((u16*)out)[idx] = f2bf(r);
  }
}

extern "C" void kernel_launch(void* const* d_in, const int* in_sizes, int n_in,
                              void* d_out, int out_size, void* d_ws, size_t ws_size,
                              hipStream_t stream) {
  const void* x   = d_in[0];
  const int*  ei  = (const int*)d_in[1];
  const void* W1  = d_in[2];
  const void* a1s = d_in[3];
  const void* a1d = d_in[4];
  const void* b1  = d_in[5];
  const void* gam = d_in[6];
  const void* bet = d_in[7];
  const void* W2  = d_in[8];
  const void* a2s = d_in[9];
  const void* a2d = d_in[10];
  const void* b2  = d_in[11];

  char* ws = (char*)d_ws;
  size_t off = 0;
  auto alloc = [&](size_t bytes) -> void* {
    void* p = ws + off;
    off += (bytes + 255) & ~(size_t)255;
    return p;
  };
  int* flags = (int*)alloc(256);
  char* zreg = (char*)alloc(2048);  // totals[196] | gsum[128] | gsq[128]
  int* totals = (int*)zreg;
  float* gsum = (float*)(zreg + 1024);
  float* gsq  = gsum + 128;
  int* H  = (int*)alloc((size_t)NBK * NBLK * 4);
  int* P  = (int*)alloc((size_t)NBK * NBLK * 4);
  int* bucketBase = (int*)alloc(1024);
  u32* ebuf = (u32*)alloc((size_t)N_EDGES * 4);
  int* csr = (int*)alloc((size_t)N_EDGES * 4);
  int* row_start = (int*)alloc((size_t)N_NODES * 4);
  int* deg = (int*)alloc((size_t)N_NODES * 4);
  float* smallf = (float*)alloc(832 * 4);
  float* a1sf = smallf;        float* a1df = smallf + 128;
  float* b1f  = smallf + 256;  float* gamf = smallf + 384;
  float* betf = smallf + 512;  float* a2sf = smallf + 640;
  float* a2df = smallf + 704;  float* b2f  = smallf + 768;
  u16* w1t = (u16*)alloc(16384 * 2);
  u16* w2t = (u16*)alloc(8192 * 2);
  u16* h1r  = (u16*)alloc((size_t)4 * QSTRIDE * 2);  // quarter-split h1
  u16* h1ob = (u16*)alloc((size_t)N_NODES * 128 * 2);
  u16* h2q  = (u16*)alloc((size_t)2 * QSTRIDE * 2);  // quarter-split h2
  float* al1s = (float*)alloc((size_t)N_NODES * 8 * 4);
  float* al1d = (float*)alloc((size_t)N_NODES * 8 * 4);
  float* scale = (float*)alloc(512);
  float* shift = (float*)alloc(512);
  float* al2s = (float*)alloc((size_t)N_NODES * 4);
  float* al2d = (float*)alloc((size_t)N_NODES * 4);
  if (off > ws_size) return;

  hipMemsetAsync(zreg, 0, 2048, stream);
  k_detect<<<1, 256, 0, stream>>>((const u16*)x, (const u32*)ei, flags);
  k_convsmall<<<100, 256, 0, stream>>>(a1s, a1d, b1, gam, bet, a2s, a2d, b2, W1, W2,
                                       smallf, w1t, w2t, flags);

  // ---- CSR build ----
  k_hist<<<NBLK, 256, 0, stream>>>(ei, H, totals, flags);
  k_scan_tot<<<1, 256, 0, stream>>>(totals, bucketBase);
  k_scan_blk<<<NBK, 256, 0, stream>>>(H, bucketBase, P);
  k_bucket<<<NBLK, 256, 0, stream>>>(ei, P, ebuf, flags);
  k_csr<<<NBK, 256, 0, stream>>>(ebuf, bucketBase, row_start, deg, csr, N_NODES);

  // ---- layer 1 (alpha1 fused into GEMM epilogue) ----
  k_gemm_mfma<128, false, true, true><<<(N_NODES + 63) / 64, 256, 0, stream>>>(
      x, w1t, nullptr, nullptr, a1sf, a1df, al1s, al1d, h1r, N_NODES, flags);
  k_agg1<<<4 * 12500, 256, 0, stream>>>(h1r, al1s, al1d, csr, row_start, deg,
                                        b1f, h1ob, N_NODES);

  // ---- BN ----
  k_bnstat<<<(N_NODES + 127) / 128, 256, 0, stream>>>(h1ob, gsum, gsq, N_NODES);
  k_bnfin<<<1, 128, 0, stream>>>(gsum, gsq, gamf, betf, scale, shift, N_NODES);

  // ---- layer 2 (alpha2 fused into GEMM epilogue) ----
  k_gemm_mfma<64, true, false, false><<<(N_NODES + 63) / 64, 256, 0, stream>>>(
      h1ob, w2t, scale, shift, a2sf, a2df, al2s, al2d, h2q, N_NODES, flags);
  k_agg2<<<2 * 12500, 256, 0, stream>>>(h2q, al2s, al2d, csr, row_start, deg,
                                        b2f, d_out, flags, N_NODES);
}

// Round 8
// 370.021 us; speedup vs baseline: 1.3667x; 1.3667x over previous
//
#include <hip/hip_runtime.h>
#include <hip/hip_bf16.h>

#define N_NODES 50000
#define N_EDGES 1600000
#define HEADS 8
#define NBK 196   // buckets: dst>>8
#define NBLK 196  // edge tiles: 196*8192 >= 1.6M
#define EPB 8192  // edges per bucket-build block

typedef unsigned short u16;
typedef unsigned char u8;
typedef unsigned int u32;
typedef __attribute__((ext_vector_type(8))) short bf16x8;
typedef __attribute__((ext_vector_type(4))) float f32x4;

__device__ __forceinline__ float bf2f(u16 u) {
  union { u32 i; float f; } v; v.i = ((u32)u) << 16; return v.f;
}
__device__ __forceinline__ float bflo(u32 p) {
  union { u32 i; float f; } v; v.i = p << 16; return v.f;
}
__device__ __forceinline__ float bfhi(u32 p) {
  union { u32 i; float f; } v; v.i = p & 0xffff0000u; return v.f;
}
__device__ __forceinline__ u16 f2bf(float f) {
  union { float f; u32 i; } v; v.f = f;
  u32 r = v.i + 0x7fff + ((v.i >> 16) & 1);  // RNE
  return (u16)(r >> 16);
}
__device__ __forceinline__ u32 pack2(float a, float b) {
  return (u32)f2bf(a) | ((u32)f2bf(b) << 16);
}
__device__ __forceinline__ int rfl(int x) { return __builtin_amdgcn_readfirstlane(x); }

// ---------------- dtype auto-detection ----------------
__global__ void k_detect(const u16* __restrict__ x, const u32* __restrict__ ei,
                         int* __restrict__ flags) {
  __shared__ int cbig, cnz;
  if (threadIdx.x == 0) { cbig = 0; cnz = 0; }
  __syncthreads();
  int lb = 0, ln = 0;
  for (int i = threadIdx.x; i < 4096; i += 256) {
    int ex = (x[i] >> 7) & 0xff;
    lb += (ex >= 140);
    if (i < 2048) ln += (ei[2 * i + 1] != 0);
  }
  atomicAdd(&cbig, lb); atomicAdd(&cnz, ln);
  __syncthreads();
  if (threadIdx.x == 0) {
    flags[0] = (cbig > 16) ? 1 : 0;   // 1: floats are fp32
    flags[1] = (cnz == 0) ? 1 : 0;    // 1: edge_index is int64
  }
}

// ---------------- converter: vectors -> fp32, W1/W2 -> transposed bf16 -------
__global__ void k_convsmall(const void* a1s, const void* a1d, const void* b1,
                            const void* gam, const void* bet, const void* a2s,
                            const void* a2d, const void* b2, const void* W1,
                            const void* W2, float* __restrict__ smallf,
                            u16* __restrict__ w1t, u16* __restrict__ w2t,
                            const int* __restrict__ flags) {
  int i = blockIdx.x * 256 + threadIdx.x;
  if (i >= 25408) return;
  bool f32 = flags[0] != 0;
  auto ld = [&](const void* p, int off) -> float {
    return f32 ? ((const float*)p)[off] : bf2f(((const u16*)p)[off]);
  };
  if (i >= 17216) {            // W2T[n][k], n<64, k<128  <- W2[k*64+n]
    int j = i - 17216, n = j >> 7, k = j & 127;
    w2t[j] = f2bf(ld(W2, k * 64 + n));
  } else if (i >= 832) {       // W1T[n][k], n<128, k<128 <- W1[k*128+n]
    int j = i - 832, n = j >> 7, k = j & 127;
    w1t[j] = f2bf(ld(W1, k * 128 + n));
  } else {
    const void* src; int off;
    if (i >= 768)      { src = b2;  off = i - 768; }
    else if (i >= 704) { src = a2d; off = i - 704; }
    else if (i >= 640) { src = a2s; off = i - 640; }
    else if (i >= 512) { src = bet; off = i - 512; }
    else if (i >= 384) { src = gam; off = i - 384; }
    else if (i >= 256) { src = b1;  off = i - 256; }
    else if (i >= 128) { src = a1d; off = i - 128; }
    else               { src = a1s; off = i; }
    smallf[i] = ld(src, off);
  }
}

// ---------------- CSR build (atomic-free two-level counting sort) ----------
__global__ __launch_bounds__(256) void k_hist(const int* __restrict__ ei,
                                              int* __restrict__ H,
                                              int* __restrict__ totals,
                                              const int* __restrict__ flags) {
  __shared__ int hist[NBK];
  int t = threadIdx.x, blk = blockIdx.x;
  for (int i = t; i < NBK; i += 256) hist[i] = 0;
  __syncthreads();
  bool i64 = flags[1] != 0;
  int base = blk * EPB;
  for (int k = 0; k < 32; k++) {
    int e = base + k * 256 + t;
    if (e < N_EDGES) {
      int d = i64 ? ei[2 * (N_EDGES + e)] : ei[N_EDGES + e];
      atomicAdd(&hist[d >> 8], 1);
    }
  }
  __syncthreads();
  for (int i = t; i < NBK; i += 256) {
    H[i * NBLK + blk] = hist[i];
    atomicAdd(&totals[i], hist[i]);
  }
}

__global__ void k_scan_tot(const int* __restrict__ totals, int* __restrict__ bucketBase) {
  __shared__ int tmp[256];
  int t = threadIdx.x;
  int v = (t < NBK) ? totals[t] : 0;
  tmp[t] = v; __syncthreads();
  for (int o = 1; o < 256; o <<= 1) {
    int x = (t >= o) ? tmp[t - o] : 0; __syncthreads();
    tmp[t] += x; __syncthreads();
  }
  if (t < NBK) bucketBase[t] = tmp[t] - v;
  if (t == NBK - 1) bucketBase[NBK] = tmp[t];
}

__global__ void k_scan_blk(const int* __restrict__ H, const int* __restrict__ bucketBase,
                           int* __restrict__ P) {
  __shared__ int tmp[256];
  int t = threadIdx.x, b = blockIdx.x;
  int v = (t < NBLK) ? H[b * NBLK + t] : 0;
  tmp[t] = v; __syncthreads();
  for (int o = 1; o < 256; o <<= 1) {
    int x = (t >= o) ? tmp[t - o] : 0; __syncthreads();
    tmp[t] += x; __syncthreads();
  }
  if (t < NBLK) P[b * NBLK + t] = bucketBase[b] + tmp[t] - v;
}

// LDS counting sort per 8192-edge tile, coalesced global writes.
__global__ __launch_bounds__(256) void k_bucket(const int* __restrict__ ei,
                                                const int* __restrict__ P,
                                                u32* __restrict__ buf,
                                                const int* __restrict__ flags) {
  __shared__ u32 sv[EPB];
  __shared__ u16 rank[EPB];
  __shared__ u8  sk8[EPB];
  __shared__ int cnt[NBK], scn[NBK], tmp[256];
  int t = threadIdx.x, blk = blockIdx.x;
  int base = blk * EPB;
  int nE = N_EDGES - base; if (nE > EPB) nE = EPB;
  for (int i = t; i < NBK; i += 256) cnt[i] = 0;
  __syncthreads();
  bool i64 = flags[1] != 0;
  for (int k = 0; k < EPB / 256; k++) {
    int li = k * 256 + t, e = base + li;
    if (li < nE) {
      int d = i64 ? ei[2 * (N_EDGES + e)] : ei[N_EDGES + e];
      rank[li] = (u16)atomicAdd(&cnt[d >> 8], 1);
    }
  }
  __syncthreads();
  int v = (t < NBK) ? cnt[t] : 0;
  tmp[t] = v; __syncthreads();
  for (int o = 1; o < 256; o <<= 1) {
    int x = (t >= o) ? tmp[t - o] : 0; __syncthreads();
    tmp[t] += x; __syncthreads();
  }
  if (t < NBK) scn[t] = tmp[t] - v;
  __syncthreads();
  for (int k = 0; k < EPB / 256; k++) {
    int li = k * 256 + t, e = base + li;
    if (li < nE) {
      int s = i64 ? ei[2 * e] : ei[e];
      int d = i64 ? ei[2 * (N_EDGES + e)] : ei[N_EDGES + e];
      int key = d >> 8;
      int pos = scn[key] + rank[li];
      sv[pos] = ((u32)(d & 255) << 16) | (u32)s;
      sk8[pos] = (u8)key;
    }
  }
  __syncthreads();
  for (int i = t; i < nE; i += 256) {
    int b = sk8[i];
    buf[P[b * NBLK + blk] + (i - scn[b])] = sv[i];
  }
}

__global__ __launch_bounds__(256) void k_csr(const u32* __restrict__ buf,
                                             const int* __restrict__ bucketBase,
                                             int* __restrict__ row_start,
                                             int* __restrict__ deg,
                                             int* __restrict__ csr, int N) {
  __shared__ int cnt[256], scn[256], cur[256];
  int b = blockIdx.x, t = threadIdx.x;
  int lo = bucketBase[b], hi = bucketBase[b + 1];
  cnt[t] = 0; __syncthreads();
  for (int e = lo + t; e < hi; e += 256) atomicAdd(&cnt[(buf[e] >> 16) & 255], 1);
  __syncthreads();
  int v = cnt[t];
  scn[t] = v; __syncthreads();
  for (int o = 1; o < 256; o <<= 1) {
    int x = (t >= o) ? scn[t - o] : 0; __syncthreads();
    scn[t] += x; __syncthreads();
  }
  int excl = scn[t] - v;
  int node = b * 256 + t;
  if (node < N) { row_start[node] = lo + excl; deg[node] = v; }
  cur[t] = lo + excl;
  __syncthreads();
  for (int e = lo + t; e < hi; e += 256) {
    u32 p = buf[e];
    int pos = atomicAdd(&cur[(p >> 16) & 255], 1);
    csr[pos] = p & 0xffff;
  }
}

// ---------------- MFMA GEMM: A[M,128] x BT[NCOLS,128] -> bf16 C row-major ---
// ALPHA1 (layer1): per-head (=per-nt) dots -> as_out/ad_out [row*8+nt]
// EPI (layer2): BN+ELU fused on A-load; alpha2 dots -> as_out/ad_out [row]
template <int NCOLS, bool EPI, bool ALPHA1, bool AFLAG>
__global__ __launch_bounds__(256) void k_gemm_mfma(const void* __restrict__ A,
                                                   const u16* __restrict__ BT,
                                                   const float* __restrict__ scale,
                                                   const float* __restrict__ shift,
                                                   const float* __restrict__ va,
                                                   const float* __restrict__ vb,
                                                   float* __restrict__ as_out,
                                                   float* __restrict__ ad_out,
                                                   u16* __restrict__ C, int M,
                                                   const int* __restrict__ flags) {
  constexpr int KP = 136;
  constexpr int NT = NCOLS / 16;
  __shared__ u16 As[64 * KP];
  __shared__ u16 Bs[NCOLS * KP];
  int t = threadIdx.x;
  int row0 = blockIdx.x * 64;
  bool af32 = AFLAG ? (flags[0] != 0) : false;

  for (int i = t; i < NCOLS * 16; i += 256) {
    int n = i >> 4, q = i & 15;
    *(uint4*)&Bs[n * KP + q * 8] = ((const uint4*)BT)[n * 16 + q];
  }
  for (int i = t; i < 64 * 32; i += 256) {
    int r = i >> 5, c4 = i & 31;
    int row = row0 + r;
    uint2 pk = make_uint2(0u, 0u);
    if (row < M) {
      if (EPI) {
        uint2 p = ((const uint2*)A)[(size_t)row * 32 + c4];
        int c = c4 * 4;
        float v0 = bflo(p.x), v1 = bfhi(p.x), v2 = bflo(p.y), v3 = bfhi(p.y);
        v0 = fmaf(v0, scale[c],     shift[c]);     v0 = v0 > 0.f ? v0 : __expf(v0) - 1.f;
        v1 = fmaf(v1, scale[c + 1], shift[c + 1]); v1 = v1 > 0.f ? v1 : __expf(v1) - 1.f;
        v2 = fmaf(v2, scale[c + 2], shift[c + 2]); v2 = v2 > 0.f ? v2 : __expf(v2) - 1.f;
        v3 = fmaf(v3, scale[c + 3], shift[c + 3]); v3 = v3 > 0.f ? v3 : __expf(v3) - 1.f;
        pk.x = pack2(v0, v1); pk.y = pack2(v2, v3);
      } else if (af32) {
        float4 v = ((const float4*)A)[(size_t)row * 32 + c4];
        pk.x = pack2(v.x, v.y); pk.y = pack2(v.z, v.w);
      } else {
        pk = ((const uint2*)A)[(size_t)row * 32 + c4];
      }
    }
    *(uint2*)&As[r * KP + c4 * 4] = pk;
  }
  __syncthreads();

  int lane = t & 63, w = t >> 6;
  int m = lane & 15, quad = lane >> 4;
  f32x4 acc[NT];
#pragma unroll
  for (int nt = 0; nt < NT; nt++) acc[nt] = (f32x4)(0.f);
  const u16* aBase = &As[(w * 16 + m) * KP + quad * 8];
  const u16* bBase = &Bs[m * KP + quad * 8];
#pragma unroll
  for (int ks = 0; ks < 4; ks++) {
    bf16x8 af = *(const bf16x8*)(aBase + ks * 32);
#pragma unroll
    for (int nt = 0; nt < NT; nt++) {
      bf16x8 bf = *(const bf16x8*)(bBase + nt * 16 * KP + ks * 32);
      acc[nt] = __builtin_amdgcn_mfma_f32_16x16x32_bf16(af, bf, acc[nt], 0, 0, 0);
    }
  }
  int orow0 = row0 + w * 16 + quad * 4;
#pragma unroll
  for (int nt = 0; nt < NT; nt++) {
#pragma unroll
    for (int r = 0; r < 4; r++) {
      int row = orow0 + r;
      if (row < M) C[(size_t)row * NCOLS + nt * 16 + m] = f2bf(acc[nt][r]);
    }
  }
  if (ALPHA1) {  // per-head dots: head == nt (16 ch/head)
    float pav[NT], pbv[NT];
#pragma unroll
    for (int nt = 0; nt < NT; nt++) { pav[nt] = va[nt * 16 + m]; pbv[nt] = vb[nt * 16 + m]; }
#pragma unroll
    for (int r = 0; r < 4; r++) {
      int row = orow0 + r;
#pragma unroll
      for (int nt = 0; nt < NT; nt++) {
        float vs = acc[nt][r] * pav[nt];
        float vd = acc[nt][r] * pbv[nt];
        vs += __shfl_xor(vs, 1); vd += __shfl_xor(vd, 1);
        vs += __shfl_xor(vs, 2); vd += __shfl_xor(vd, 2);
        vs += __shfl_xor(vs, 4); vd += __shfl_xor(vd, 4);
        vs += __shfl_xor(vs, 8); vd += __shfl_xor(vd, 8);
        if (row < M && m == 0) { as_out[row * 8 + nt] = vs; ad_out[row * 8 + nt] = vd; }
      }
    }
  }
  if (EPI) {  // fused alpha2
    float pav[NT], pbv[NT];
#pragma unroll
    for (int nt = 0; nt < NT; nt++) { pav[nt] = va[nt * 16 + m]; pbv[nt] = vb[nt * 16 + m]; }
#pragma unroll
    for (int r = 0; r < 4; r++) {
      float vs = 0.f, vd = 0.f;
#pragma unroll
      for (int nt = 0; nt < NT; nt++) {
        vs = fmaf(acc[nt][r], pav[nt], vs);
        vd = fmaf(acc[nt][r], pbv[nt], vd);
      }
      vs += __shfl_xor(vs, 1); vd += __shfl_xor(vd, 1);
      vs += __shfl_xor(vs, 2); vd += __shfl_xor(vd, 2);
      vs += __shfl_xor(vs, 4); vd += __shfl_xor(vd, 4);
      vs += __shfl_xor(vs, 8); vd += __shfl_xor(vd, 8);
      int row = orow0 + r;
      if (row < M && m == 0) { as_out[row] = vs; ad_out[row] = vd; }
    }
  }
}

// ---------------- aggregation layer 1: shared-exp, uint2 gathers, BN fused --
// exp role: head = l>>3, sub = l&7 (64 lanes = 8 edges x 8 heads)
// gather role: eh = l>>5 (edge parity), c2 = l&31 (4 channels 4*c2..+3)
__global__ __launch_bounds__(256) void k_agg1(const u16* __restrict__ h1b,
                                              const float* __restrict__ as_,
                                              const float* __restrict__ ad_,
                                              const int* __restrict__ csr,
                                              const int* __restrict__ row_start,
                                              const int* __restrict__ deg,
                                              const float* __restrict__ b1,
                                              u16* __restrict__ out,
                                              float* __restrict__ bnrep, int N) {
  __shared__ float lsum[128], lsq[128];
  int t = threadIdx.x;
  if (t < 128) { lsum[t] = 0.f; lsq[t] = 0.f; }
  __syncthreads();
  int node = blockIdx.x * 4 + (t >> 6);
  int l = t & 63;
  int head = l >> 3, sub = l & 7;
  int eh = l >> 5, c2 = l & 31;
  int hch = c2 >> 2;
  if (node < N) {
    int node_u = rfl(node);
    int st = rfl(row_start[node_u]);
    int cnt = rfl(deg[node_u]);
    const int* cp = csr + st;
    const uint2* h2p = (const uint2*)h1b;
    float ad = ad_[(node_u << 3) | head];
    float sp = 0.f, a0 = 0.f, a1 = 0.f, a2 = 0.f, a3 = 0.f;
    int j = 0;
    for (; j + 8 <= cnt; j += 8) {
      int ssub = cp[j + sub];                   // per-lane vector load
      float e = as_[(ssub << 3) | head] + ad;
      e = fmaxf(e, 0.2f * e);
      float p = __expf(e);
      sp += p;
#pragma unroll
      for (int k = 0; k < 4; k++) {
        int se = cp[j + 2 * k], so = cp[j + 2 * k + 1];  // uniform -> s_load
        int sk = eh ? so : se;
        float pk = __shfl(p, (hch << 3) | (2 * k + eh));
        uint2 hv = h2p[(size_t)sk * 32 + c2];
        a0 = fmaf(pk, bflo(hv.x), a0); a1 = fmaf(pk, bfhi(hv.x), a1);
        a2 = fmaf(pk, bflo(hv.y), a2); a3 = fmaf(pk, bfhi(hv.y), a3);
      }
    }
    for (; j <= cnt; j++) {  // tail edges, then self-loop at j==cnt
      int s0 = (j < cnt) ? rfl(cp[j]) : node_u;
      float e = as_[(s0 << 3) | head] + ad;
      e = fmaxf(e, 0.2f * e);
      float p = __expf(e);
      if (sub == 0) sp += p;
      float pk = __shfl(p, hch << 3);
      if (eh == 0) {
        uint2 hv = h2p[(size_t)s0 * 32 + c2];
        a0 = fmaf(pk, bflo(hv.x), a0); a1 = fmaf(pk, bfhi(hv.x), a1);
        a2 = fmaf(pk, bflo(hv.y), a2); a3 = fmaf(pk, bfhi(hv.y), a3);
      }
    }
    sp += __shfl_xor(sp, 1);
    sp += __shfl_xor(sp, 2);
    sp += __shfl_xor(sp, 4);
    float inv = 1.f / (__shfl(sp, hch << 3) + 1e-16f);
    a0 += __shfl_xor(a0, 32); a1 += __shfl_xor(a1, 32);
    a2 += __shfl_xor(a2, 32); a3 += __shfl_xor(a3, 32);
    if (eh == 0) {
      int c0 = c2 * 4;
      float r0 = fmaf(a0, inv, b1[c0]);
      float r1 = fmaf(a1, inv, b1[c0 + 1]);
      float r2 = fmaf(a2, inv, b1[c0 + 2]);
      float r3 = fmaf(a3, inv, b1[c0 + 3]);
      ((uint2*)out)[(size_t)node_u * 32 + c2] = make_uint2(pack2(r0, r1), pack2(r2, r3));
      atomicAdd(&lsum[c0], r0);     atomicAdd(&lsq[c0], r0 * r0);
      atomicAdd(&lsum[c0 + 1], r1); atomicAdd(&lsq[c0 + 1], r1 * r1);
      atomicAdd(&lsum[c0 + 2], r2); atomicAdd(&lsq[c0 + 2], r2 * r2);
      atomicAdd(&lsum[c0 + 3], r3); atomicAdd(&lsq[c0 + 3], r3 * r3);
    }
  }
  __syncthreads();
  if (t < 128) {
    int rep = (blockIdx.x & 31) * 256;
    atomicAdd(&bnrep[rep + t], lsum[t]);
    atomicAdd(&bnrep[rep + 128 + t], lsq[t]);
  }
}

// ---------------- BN finalize: reduce 32 replicas ----------------
__global__ void k_bnfin(const float* __restrict__ bnrep,
                        const float* __restrict__ gamma, const float* __restrict__ beta,
                        float* __restrict__ scale, float* __restrict__ shift, int N) {
  int t = threadIdx.x;
  if (t >= 128) return;
  float s = 0.f, q = 0.f;
  for (int r = 0; r < 32; r++) {
    s += bnrep[r * 256 + t];
    q += bnrep[r * 256 + 128 + t];
  }
  float mu = s / (float)N;
  float var = fmaxf(q / (float)N - mu * mu, 0.f);
  float sc = gamma[t] * rsqrtf(var + 1e-5f);
  scale[t] = sc;
  shift[t] = beta[t] - mu * sc;
}

// ---------------- aggregation layer 2 -> output (uint2 gathers) -------------
// exp role: sub = l (l<8). gather role: e4 = l>>4 (edge slot), c4 = l&15.
__global__ __launch_bounds__(256) void k_agg2(const u16* __restrict__ h2b,
                                              const float* __restrict__ as_,
                                              const float* __restrict__ ad_,
                                              const int* __restrict__ csr,
                                              const int* __restrict__ row_start,
                                              const int* __restrict__ deg,
                                              const float* __restrict__ b2,
                                              void* __restrict__ out,
                                              const int* __restrict__ flags, int N) {
  int node = blockIdx.x * 4 + (threadIdx.x >> 6);
  if (node >= N) return;
  int l = threadIdx.x & 63;
  int sub = l & 7;
  int e4 = l >> 4, c4 = l & 15;
  int node_u = rfl(node);
  int st = rfl(row_start[node_u]);
  int cnt = rfl(deg[node_u]);
  const int* cp = csr + st;
  const uint2* h2p = (const uint2*)h2b;
  float ad = ad_[node_u];
  float sp = 0.f, a0 = 0.f, a1 = 0.f, a2 = 0.f, a3 = 0.f;
  int j = 0;
  for (; j + 8 <= cnt; j += 8) {
    int ssub = cp[j + sub];
    float e = as_[ssub] + ad;
    e = fmaxf(e, 0.2f * e);
    float p = __expf(e);
    if (l < 8) sp += p;
#pragma unroll
    for (int pass = 0; pass < 2; pass++) {
      int sa = cp[j + 4 * pass], sb = cp[j + 4 * pass + 1];
      int sc = cp[j + 4 * pass + 2], sd = cp[j + 4 * pass + 3];
      int sk = (e4 == 0) ? sa : (e4 == 1) ? sb : (e4 == 2) ? sc : sd;
      float pk = __shfl(p, 4 * pass + e4);
      uint2 hv = h2p[(size_t)sk * 16 + c4];
      a0 = fmaf(pk, bflo(hv.x), a0); a1 = fmaf(pk, bfhi(hv.x), a1);
      a2 = fmaf(pk, bflo(hv.y), a2); a3 = fmaf(pk, bfhi(hv.y), a3);
    }
  }
  for (; j <= cnt; j++) {  // tail + self-loop
    int s0 = (j < cnt) ? rfl(cp[j]) : node_u;
    float e = as_[s0] + ad;
    e = fmaxf(e, 0.2f * e);
    float p = __expf(e);
    if (l == 0) sp += p;
    float pk = __shfl(p, 0);
    if (e4 == 0) {
      uint2 hv = h2p[(size_t)s0 * 16 + c4];
      a0 = fmaf(pk, bflo(hv.x), a0); a1 = fmaf(pk, bfhi(hv.x), a1);
      a2 = fmaf(pk, bflo(hv.y), a2); a3 = fmaf(pk, bfhi(hv.y), a3);
    }
  }
  sp += __shfl_xor(sp, 1);
  sp += __shfl_xor(sp, 2);
  sp += __shfl_xor(sp, 4);
  float inv = 1.f / (__shfl(sp, 0) + 1e-16f);
  a0 += __shfl_xor(a0, 16); a1 += __shfl_xor(a1, 16);
  a2 += __shfl_xor(a2, 16); a3 += __shfl_xor(a3, 16);
  a0 += __shfl_xor(a0, 32); a1 += __shfl_xor(a1, 32);
  a2 += __shfl_xor(a2, 32); a3 += __shfl_xor(a3, 32);
  if (e4 == 0) {
    int c0 = c4 * 4;
    float r0 = fmaf(a0, inv, b2[c0]);
    float r1 = fmaf(a1, inv, b2[c0 + 1]);
    float r2 = fmaf(a2, inv, b2[c0 + 2]);
    float r3 = fmaf(a3, inv, b2[c0 + 3]);
    if (flags[0]) {
      ((float4*)out)[(size_t)node_u * 16 + c4] = make_float4(r0, r1, r2, r3);
    } else {
      ((uint2*)out)[(size_t)node_u * 16 + c4] = make_uint2(pack2(r0, r1), pack2(r2, r3));
    }
  }
}

extern "C" void kernel_launch(void* const* d_in, const int* in_sizes, int n_in,
                              void* d_out, int out_size, void* d_ws, size_t ws_size,
                              hipStream_t stream) {
  const void* x   = d_in[0];
  const int*  ei  = (const int*)d_in[1];
  const void* W1  = d_in[2];
  const void* a1s = d_in[3];
  const void* a1d = d_in[4];
  const void* b1  = d_in[5];
  const void* gam = d_in[6];
  const void* bet = d_in[7];
  const void* W2  = d_in[8];
  const void* a2s = d_in[9];
  const void* a2d = d_in[10];
  const void* b2  = d_in[11];

  char* ws = (char*)d_ws;
  size_t off = 0;
  auto alloc = [&](size_t bytes) -> void* {
    void* p = ws + off;
    off += (bytes + 255) & ~(size_t)255;
    return p;
  };
  int* flags = (int*)alloc(256);
  // zero region: totals[196] pad to 1024B | bnrep[32*256 floats = 32KB]
  char* zreg = (char*)alloc(1024 + 32 * 256 * 4);
  int* totals = (int*)zreg;
  float* bnrep = (float*)(zreg + 1024);
  int* H  = (int*)alloc((size_t)NBK * NBLK * 4);
  int* P  = (int*)alloc((size_t)NBK * NBLK * 4);
  int* bucketBase = (int*)alloc(1024);
  u32* ebuf = (u32*)alloc((size_t)N_EDGES * 4);
  int* csr = (int*)alloc((size_t)N_EDGES * 4);
  int* row_start = (int*)alloc((size_t)N_NODES * 4);
  int* deg = (int*)alloc((size_t)N_NODES * 4);
  float* smallf = (float*)alloc(832 * 4);
  float* a1sf = smallf;        float* a1df = smallf + 128;
  float* b1f  = smallf + 256;  float* gamf = smallf + 384;
  float* betf = smallf + 512;  float* a2sf = smallf + 640;
  float* a2df = smallf + 704;  float* b2f  = smallf + 768;
  u16* w1t = (u16*)alloc(16384 * 2);
  u16* w2t = (u16*)alloc(8192 * 2);
  u16* h1b  = (u16*)alloc((size_t)N_NODES * 128 * 2);
  u16* h1ob = (u16*)alloc((size_t)N_NODES * 128 * 2);
  u16* h2b  = (u16*)alloc((size_t)N_NODES * 64 * 2);
  float* al1s = (float*)alloc((size_t)N_NODES * 8 * 4);
  float* al1d = (float*)alloc((size_t)N_NODES * 8 * 4);
  float* scale = (float*)alloc(512);
  float* shift = (float*)alloc(512);
  float* al2s = (float*)alloc((size_t)N_NODES * 4);
  float* al2d = (float*)alloc((size_t)N_NODES * 4);
  if (off > ws_size) return;

  hipMemsetAsync(zreg, 0, 1024 + 32 * 256 * 4, stream);
  k_detect<<<1, 256, 0, stream>>>((const u16*)x, (const u32*)ei, flags);
  k_convsmall<<<100, 256, 0, stream>>>(a1s, a1d, b1, gam, bet, a2s, a2d, b2, W1, W2,
                                       smallf, w1t, w2t, flags);

  // ---- CSR build ----
  k_hist<<<NBLK, 256, 0, stream>>>(ei, H, totals, flags);
  k_scan_tot<<<1, 256, 0, stream>>>(totals, bucketBase);
  k_scan_blk<<<NBK, 256, 0, stream>>>(H, bucketBase, P);
  k_bucket<<<NBLK, 256, 0, stream>>>(ei, P, ebuf, flags);
  k_csr<<<NBK, 256, 0, stream>>>(ebuf, bucketBase, row_start, deg, csr, N_NODES);

  // ---- layer 1 (alpha1 fused into GEMM epilogue; BN stats fused into agg1) --
  k_gemm_mfma<128, false, true, true><<<(N_NODES + 63) / 64, 256, 0, stream>>>(
      x, w1t, nullptr, nullptr, a1sf, a1df, al1s, al1d, h1b, N_NODES, flags);
  k_agg1<<<(N_NODES + 3) / 4, 256, 0, stream>>>(h1b, al1s, al1d, csr, row_start, deg,
                                                b1f, h1ob, bnrep, N_NODES);
  k_bnfin<<<1, 128, 0, stream>>>(bnrep, gamf, betf, scale, shift, N_NODES);

  // ---- layer 2 (alpha2 fused into GEMM epilogue) ----
  k_gemm_mfma<64, true, false, false><<<(N_NODES + 63) / 64, 256, 0, stream>>>(
      h1ob, w2t, scale, shift, a2sf, a2df, al2s, al2d, h2b, N_NODES, flags);
  k_agg2<<<(N_NODES + 3) / 4, 256, 0, stream>>>(h2b, al2s, al2d, csr, row_start, deg,
                                                b2f, d_out, flags, N_NODES);
}

// Round 9
// 357.666 us; speedup vs baseline: 1.4139x; 1.0345x over previous
//
#include <hip/hip_runtime.h>
#include <hip/hip_bf16.h>

#define N_NODES 50000
#define N_EDGES 1600000
#define HEADS 8
#define NBK 196   // buckets: dst>>8
#define NBLK 196  // edge tiles: 196*8192 >= 1.6M
#define EPB 8192  // edges per bucket-build block

typedef unsigned short u16;
typedef unsigned char u8;
typedef unsigned int u32;
typedef __attribute__((ext_vector_type(8))) short bf16x8;
typedef __attribute__((ext_vector_type(4))) float f32x4;

__device__ __forceinline__ float bf2f(u16 u) {
  union { u32 i; float f; } v; v.i = ((u32)u) << 16; return v.f;
}
__device__ __forceinline__ float bflo(u32 p) {
  union { u32 i; float f; } v; v.i = p << 16; return v.f;
}
__device__ __forceinline__ float bfhi(u32 p) {
  union { u32 i; float f; } v; v.i = p & 0xffff0000u; return v.f;
}
__device__ __forceinline__ u16 f2bf(float f) {
  union { float f; u32 i; } v; v.f = f;
  u32 r = v.i + 0x7fff + ((v.i >> 16) & 1);  // RNE
  return (u16)(r >> 16);
}
__device__ __forceinline__ u32 pack2(float a, float b) {
  return (u32)f2bf(a) | ((u32)f2bf(b) << 16);
}
__device__ __forceinline__ int rfl(int x) { return __builtin_amdgcn_readfirstlane(x); }

// ---------------- dtype auto-detection ----------------
__global__ void k_detect(const u16* __restrict__ x, const u32* __restrict__ ei,
                         int* __restrict__ flags) {
  __shared__ int cbig, cnz;
  if (threadIdx.x == 0) { cbig = 0; cnz = 0; }
  __syncthreads();
  int lb = 0, ln = 0;
  for (int i = threadIdx.x; i < 4096; i += 256) {
    int ex = (x[i] >> 7) & 0xff;
    lb += (ex >= 140);
    if (i < 2048) ln += (ei[2 * i + 1] != 0);
  }
  atomicAdd(&cbig, lb); atomicAdd(&cnz, ln);
  __syncthreads();
  if (threadIdx.x == 0) {
    flags[0] = (cbig > 16) ? 1 : 0;   // 1: floats are fp32
    flags[1] = (cnz == 0) ? 1 : 0;    // 1: edge_index is int64
  }
}

// ---------------- converter: vectors -> fp32, W1/W2 -> transposed bf16 -------
__global__ void k_convsmall(const void* a1s, const void* a1d, const void* b1,
                            const void* gam, const void* bet, const void* a2s,
                            const void* a2d, const void* b2, const void* W1,
                            const void* W2, float* __restrict__ smallf,
                            u16* __restrict__ w1t, u16* __restrict__ w2t,
                            const int* __restrict__ flags) {
  int i = blockIdx.x * 256 + threadIdx.x;
  if (i >= 25408) return;
  bool f32 = flags[0] != 0;
  auto ld = [&](const void* p, int off) -> float {
    return f32 ? ((const float*)p)[off] : bf2f(((const u16*)p)[off]);
  };
  if (i >= 17216) {            // W2T[n][k], n<64, k<128  <- W2[k*64+n]
    int j = i - 17216, n = j >> 7, k = j & 127;
    w2t[j] = f2bf(ld(W2, k * 64 + n));
  } else if (i >= 832) {       // W1T[n][k], n<128, k<128 <- W1[k*128+n]
    int j = i - 832, n = j >> 7, k = j & 127;
    w1t[j] = f2bf(ld(W1, k * 128 + n));
  } else {
    const void* src; int off;
    if (i >= 768)      { src = b2;  off = i - 768; }
    else if (i >= 704) { src = a2d; off = i - 704; }
    else if (i >= 640) { src = a2s; off = i - 640; }
    else if (i >= 512) { src = bet; off = i - 512; }
    else if (i >= 384) { src = gam; off = i - 384; }
    else if (i >= 256) { src = b1;  off = i - 256; }
    else if (i >= 128) { src = a1d; off = i - 128; }
    else               { src = a1s; off = i; }
    smallf[i] = ld(src, off);
  }
}

// ---------------- CSR build (atomic-free two-level counting sort) ----------
__global__ __launch_bounds__(256) void k_hist(const int* __restrict__ ei,
                                              int* __restrict__ H,
                                              int* __restrict__ totals,
                                              const int* __restrict__ flags) {
  __shared__ int hist[NBK];
  int t = threadIdx.x, blk = blockIdx.x;
  for (int i = t; i < NBK; i += 256) hist[i] = 0;
  __syncthreads();
  bool i64 = flags[1] != 0;
  int base = blk * EPB;
  for (int k = 0; k < 32; k++) {
    int e = base + k * 256 + t;
    if (e < N_EDGES) {
      int d = i64 ? ei[2 * (N_EDGES + e)] : ei[N_EDGES + e];
      atomicAdd(&hist[d >> 8], 1);
    }
  }
  __syncthreads();
  for (int i = t; i < NBK; i += 256) {
    H[i * NBLK + blk] = hist[i];
    atomicAdd(&totals[i], hist[i]);
  }
}

// per-bucket scan over blocks; bucketBase computed inline from totals
__global__ void k_scan_blk(const int* __restrict__ H, const int* __restrict__ totals,
                           int* __restrict__ P) {
  __shared__ int tb[256], tmp[256];
  int t = threadIdx.x, b = blockIdx.x;
  int v0 = (t < NBK) ? totals[t] : 0;
  tb[t] = v0; __syncthreads();
  for (int o = 1; o < 256; o <<= 1) {
    int x = (t >= o) ? tb[t - o] : 0; __syncthreads();
    tb[t] += x; __syncthreads();
  }
  int base = (b == 0) ? 0 : tb[b - 1];
  int v = (t < NBLK) ? H[b * NBLK + t] : 0;
  tmp[t] = v; __syncthreads();
  for (int o = 1; o < 256; o <<= 1) {
    int x = (t >= o) ? tmp[t - o] : 0; __syncthreads();
    tmp[t] += x; __syncthreads();
  }
  if (t < NBLK) P[b * NBLK + t] = base + tmp[t] - v;
}

// LDS counting sort per 8192-edge tile, coalesced global writes.
__global__ __launch_bounds__(256) void k_bucket(const int* __restrict__ ei,
                                                const int* __restrict__ P,
                                                u32* __restrict__ buf,
                                                const int* __restrict__ flags) {
  __shared__ u32 sv[EPB];
  __shared__ u16 rank[EPB];
  __shared__ u8  sk8[EPB];
  __shared__ int cnt[NBK], scn[NBK], tmp[256];
  int t = threadIdx.x, blk = blockIdx.x;
  int base = blk * EPB;
  int nE = N_EDGES - base; if (nE > EPB) nE = EPB;
  for (int i = t; i < NBK; i += 256) cnt[i] = 0;
  __syncthreads();
  bool i64 = flags[1] != 0;
  for (int k = 0; k < EPB / 256; k++) {
    int li = k * 256 + t, e = base + li;
    if (li < nE) {
      int d = i64 ? ei[2 * (N_EDGES + e)] : ei[N_EDGES + e];
      rank[li] = (u16)atomicAdd(&cnt[d >> 8], 1);
    }
  }
  __syncthreads();
  int v = (t < NBK) ? cnt[t] : 0;
  tmp[t] = v; __syncthreads();
  for (int o = 1; o < 256; o <<= 1) {
    int x = (t >= o) ? tmp[t - o] : 0; __syncthreads();
    tmp[t] += x; __syncthreads();
  }
  if (t < NBK) scn[t] = tmp[t] - v;
  __syncthreads();
  for (int k = 0; k < EPB / 256; k++) {
    int li = k * 256 + t, e = base + li;
    if (li < nE) {
      int s = i64 ? ei[2 * e] : ei[e];
      int d = i64 ? ei[2 * (N_EDGES + e)] : ei[N_EDGES + e];
      int key = d >> 8;
      int pos = scn[key] + rank[li];
      sv[pos] = ((u32)(d & 255) << 16) | (u32)s;
      sk8[pos] = (u8)key;
    }
  }
  __syncthreads();
  for (int i = t; i < nE; i += 256) {
    int b = sk8[i];
    buf[P[b * NBLK + blk] + (i - scn[b])] = sv[i];
  }
}

__global__ __launch_bounds__(256) void k_csr(const u32* __restrict__ buf,
                                             const int* __restrict__ totals,
                                             int* __restrict__ row_start,
                                             int* __restrict__ deg,
                                             int* __restrict__ csr, int N) {
  __shared__ int tb[256], cnt[256], scn[256], cur[256];
  int b = blockIdx.x, t = threadIdx.x;
  int v0 = (t < NBK) ? totals[t] : 0;
  tb[t] = v0; __syncthreads();
  for (int o = 1; o < 256; o <<= 1) {
    int x = (t >= o) ? tb[t - o] : 0; __syncthreads();
    tb[t] += x; __syncthreads();
  }
  int lo = (b == 0) ? 0 : tb[b - 1];
  int hi = tb[b];
  cnt[t] = 0; __syncthreads();
  for (int e = lo + t; e < hi; e += 256) atomicAdd(&cnt[(buf[e] >> 16) & 255], 1);
  __syncthreads();
  int v = cnt[t];
  scn[t] = v; __syncthreads();
  for (int o = 1; o < 256; o <<= 1) {
    int x = (t >= o) ? scn[t - o] : 0; __syncthreads();
    scn[t] += x; __syncthreads();
  }
  int excl = scn[t] - v;
  int node = b * 256 + t;
  if (node < N) { row_start[node] = lo + excl; deg[node] = v; }
  cur[t] = lo + excl;
  __syncthreads();
  for (int e = lo + t; e < hi; e += 256) {
    u32 p = buf[e];
    int pos = atomicAdd(&cur[(p >> 16) & 255], 1);
    csr[pos] = p & 0xffff;
  }
}

// ---------------- MFMA GEMM: A[M,128] x BT[NCOLS,128] -> bf16 C row-major ---
// ALPHA1 (layer1): per-head (=per-nt) dots -> as_out/ad_out [row*8+nt]
// EPI (layer2): BN finalize (from gsum/gsq) + BN+ELU on A-load; alpha2 dots.
template <int NCOLS, bool EPI, bool ALPHA1, bool AFLAG>
__global__ __launch_bounds__(256) void k_gemm_mfma(const void* __restrict__ A,
                                                   const u16* __restrict__ BT,
                                                   const float* __restrict__ bnsum,
                                                   const float* __restrict__ bnsq,
                                                   const float* __restrict__ gamma,
                                                   const float* __restrict__ beta,
                                                   const float* __restrict__ va,
                                                   const float* __restrict__ vb,
                                                   float* __restrict__ as_out,
                                                   float* __restrict__ ad_out,
                                                   u16* __restrict__ C, int M,
                                                   const int* __restrict__ flags) {
  constexpr int KP = 136;
  constexpr int NT = NCOLS / 16;
  __shared__ u16 As[64 * KP];
  __shared__ u16 Bs[NCOLS * KP];
  __shared__ float sSc[128], sSh[128];
  int t = threadIdx.x;
  int row0 = blockIdx.x * 64;
  bool af32 = AFLAG ? (flags[0] != 0) : false;

  if (EPI) {  // inline BN finalize (redundant per block, trivial cost)
    if (t < 128) {
      float mu = bnsum[t] * (1.f / (float)N_NODES);
      float var = fmaxf(bnsq[t] * (1.f / (float)N_NODES) - mu * mu, 0.f);
      float sc = gamma[t] * rsqrtf(var + 1e-5f);
      sSc[t] = sc; sSh[t] = beta[t] - mu * sc;
    }
    __syncthreads();
  }

  for (int i = t; i < NCOLS * 16; i += 256) {
    int n = i >> 4, q = i & 15;
    *(uint4*)&Bs[n * KP + q * 8] = ((const uint4*)BT)[n * 16 + q];
  }
  for (int i = t; i < 64 * 32; i += 256) {
    int r = i >> 5, c4 = i & 31;
    int row = row0 + r;
    uint2 pk = make_uint2(0u, 0u);
    if (row < M) {
      if (EPI) {
        uint2 p = ((const uint2*)A)[(size_t)row * 32 + c4];
        int c = c4 * 4;
        float v0 = bflo(p.x), v1 = bfhi(p.x), v2 = bflo(p.y), v3 = bfhi(p.y);
        v0 = fmaf(v0, sSc[c],     sSh[c]);     v0 = v0 > 0.f ? v0 : __expf(v0) - 1.f;
        v1 = fmaf(v1, sSc[c + 1], sSh[c + 1]); v1 = v1 > 0.f ? v1 : __expf(v1) - 1.f;
        v2 = fmaf(v2, sSc[c + 2], sSh[c + 2]); v2 = v2 > 0.f ? v2 : __expf(v2) - 1.f;
        v3 = fmaf(v3, sSc[c + 3], sSh[c + 3]); v3 = v3 > 0.f ? v3 : __expf(v3) - 1.f;
        pk.x = pack2(v0, v1); pk.y = pack2(v2, v3);
      } else if (af32) {
        float4 v = ((const float4*)A)[(size_t)row * 32 + c4];
        pk.x = pack2(v.x, v.y); pk.y = pack2(v.z, v.w);
      } else {
        pk = ((const uint2*)A)[(size_t)row * 32 + c4];
      }
    }
    *(uint2*)&As[r * KP + c4 * 4] = pk;
  }
  __syncthreads();

  int lane = t & 63, w = t >> 6;
  int m = lane & 15, quad = lane >> 4;
  f32x4 acc[NT];
#pragma unroll
  for (int nt = 0; nt < NT; nt++) acc[nt] = (f32x4)(0.f);
  const u16* aBase = &As[(w * 16 + m) * KP + quad * 8];
  const u16* bBase = &Bs[m * KP + quad * 8];
#pragma unroll
  for (int ks = 0; ks < 4; ks++) {
    bf16x8 af = *(const bf16x8*)(aBase + ks * 32);
#pragma unroll
    for (int nt = 0; nt < NT; nt++) {
      bf16x8 bf = *(const bf16x8*)(bBase + nt * 16 * KP + ks * 32);
      acc[nt] = __builtin_amdgcn_mfma_f32_16x16x32_bf16(af, bf, acc[nt], 0, 0, 0);
    }
  }
  int orow0 = row0 + w * 16 + quad * 4;
#pragma unroll
  for (int nt = 0; nt < NT; nt++) {
#pragma unroll
    for (int r = 0; r < 4; r++) {
      int row = orow0 + r;
      if (row < M) C[(size_t)row * NCOLS + nt * 16 + m] = f2bf(acc[nt][r]);
    }
  }
  if (ALPHA1) {
    float pav[NT], pbv[NT];
#pragma unroll
    for (int nt = 0; nt < NT; nt++) { pav[nt] = va[nt * 16 + m]; pbv[nt] = vb[nt * 16 + m]; }
#pragma unroll
    for (int r = 0; r < 4; r++) {
      int row = orow0 + r;
#pragma unroll
      for (int nt = 0; nt < NT; nt++) {
        float vs = acc[nt][r] * pav[nt];
        float vd = acc[nt][r] * pbv[nt];
        vs += __shfl_xor(vs, 1); vd += __shfl_xor(vd, 1);
        vs += __shfl_xor(vs, 2); vd += __shfl_xor(vd, 2);
        vs += __shfl_xor(vs, 4); vd += __shfl_xor(vd, 4);
        vs += __shfl_xor(vs, 8); vd += __shfl_xor(vd, 8);
        if (row < M && m == 0) { as_out[row * 8 + nt] = vs; ad_out[row * 8 + nt] = vd; }
      }
    }
  }
  if (EPI) {
    float pav[NT], pbv[NT];
#pragma unroll
    for (int nt = 0; nt < NT; nt++) { pav[nt] = va[nt * 16 + m]; pbv[nt] = vb[nt * 16 + m]; }
#pragma unroll
    for (int r = 0; r < 4; r++) {
      float vs = 0.f, vd = 0.f;
#pragma unroll
      for (int nt = 0; nt < NT; nt++) {
        vs = fmaf(acc[nt][r], pav[nt], vs);
        vd = fmaf(acc[nt][r], pbv[nt], vd);
      }
      vs += __shfl_xor(vs, 1); vd += __shfl_xor(vd, 1);
      vs += __shfl_xor(vs, 2); vd += __shfl_xor(vd, 2);
      vs += __shfl_xor(vs, 4); vd += __shfl_xor(vd, 4);
      vs += __shfl_xor(vs, 8); vd += __shfl_xor(vd, 8);
      int row = orow0 + r;
      if (row < M && m == 0) { as_out[row] = vs; ad_out[row] = vd; }
    }
  }
}

// ---------------- aggregation layer 1: shared-exp, uint2 gathers ------------
// exp role: head = l>>3, sub = l&7. gather role: eh = l>>5, c2 = l&31.
__global__ __launch_bounds__(256) void k_agg1(const u16* __restrict__ h1b,
                                              const float* __restrict__ as_,
                                              const float* __restrict__ ad_,
                                              const int* __restrict__ csr,
                                              const int* __restrict__ row_start,
                                              const int* __restrict__ deg,
                                              const float* __restrict__ b1,
                                              u16* __restrict__ out, int N) {
  int node = blockIdx.x * 4 + (threadIdx.x >> 6);
  if (node >= N) return;
  int l = threadIdx.x & 63;
  int head = l >> 3, sub = l & 7;
  int eh = l >> 5, c2 = l & 31;
  int hch = c2 >> 2;
  int node_u = rfl(node);
  int st = rfl(row_start[node_u]);
  int cnt = rfl(deg[node_u]);
  const int* cp = csr + st;
  const uint2* h2p = (const uint2*)h1b;
  float ad = ad_[(node_u << 3) | head];
  float sp = 0.f, a0 = 0.f, a1 = 0.f, a2 = 0.f, a3 = 0.f;
  int j = 0;
  for (; j + 8 <= cnt; j += 8) {
    int ssub = cp[j + sub];
    float e = as_[(ssub << 3) | head] + ad;
    e = fmaxf(e, 0.2f * e);
    float p = __expf(e);
    sp += p;
#pragma unroll
    for (int k = 0; k < 4; k++) {
      int se = cp[j + 2 * k], so = cp[j + 2 * k + 1];  // uniform -> s_load
      int sk = eh ? so : se;
      float pk = __shfl(p, (hch << 3) | (2 * k + eh));
      uint2 hv = h2p[(size_t)sk * 32 + c2];
      a0 = fmaf(pk, bflo(hv.x), a0); a1 = fmaf(pk, bfhi(hv.x), a1);
      a2 = fmaf(pk, bflo(hv.y), a2); a3 = fmaf(pk, bfhi(hv.y), a3);
    }
  }
  for (; j <= cnt; j++) {  // tail edges, then self-loop at j==cnt
    int s0 = (j < cnt) ? rfl(cp[j]) : node_u;
    float e = as_[(s0 << 3) | head] + ad;
    e = fmaxf(e, 0.2f * e);
    float p = __expf(e);
    if (sub == 0) sp += p;
    float pk = __shfl(p, hch << 3);
    if (eh == 0) {
      uint2 hv = h2p[(size_t)s0 * 32 + c2];
      a0 = fmaf(pk, bflo(hv.x), a0); a1 = fmaf(pk, bfhi(hv.x), a1);
      a2 = fmaf(pk, bflo(hv.y), a2); a3 = fmaf(pk, bfhi(hv.y), a3);
    }
  }
  sp += __shfl_xor(sp, 1);
  sp += __shfl_xor(sp, 2);
  sp += __shfl_xor(sp, 4);
  float inv = 1.f / (__shfl(sp, hch << 3) + 1e-16f);
  a0 += __shfl_xor(a0, 32); a1 += __shfl_xor(a1, 32);
  a2 += __shfl_xor(a2, 32); a3 += __shfl_xor(a3, 32);
  if (eh == 0) {
    int c0 = c2 * 4;
    float r0 = fmaf(a0, inv, b1[c0]);
    float r1 = fmaf(a1, inv, b1[c0 + 1]);
    float r2 = fmaf(a2, inv, b1[c0 + 2]);
    float r3 = fmaf(a3, inv, b1[c0 + 3]);
    ((uint2*)out)[(size_t)node_u * 32 + c2] = make_uint2(pack2(r0, r1), pack2(r2, r3));
  }
}

// ---------------- batch norm stats ----------------
__global__ void k_bnstat(const u16* __restrict__ h, float* __restrict__ gsum,
                         float* __restrict__ gsq, int N) {
  __shared__ float ts[256], tq[256];
  int t = threadIdx.x, col = t & 127, rr = t >> 7;
  int row0 = blockIdx.x * 128;
  float s = 0.f, q = 0.f;
  for (int r = rr; r < 128; r += 2) {
    int row = row0 + r;
    if (row < N) {
      float v = bf2f(h[((size_t)row << 7) + col]);
      s += v; q = fmaf(v, v, q);
    }
  }
  ts[t] = s; tq[t] = q; __syncthreads();
  if (t < 128) {
    atomicAdd(&gsum[t], ts[t] + ts[t + 128]);
    atomicAdd(&gsq[t], tq[t] + tq[t + 128]);
  }
}

// ---------------- aggregation layer 2 -> output (uint2 gathers) -------------
__global__ __launch_bounds__(256) void k_agg2(const u16* __restrict__ h2b,
                                              const float* __restrict__ as_,
                                              const float* __restrict__ ad_,
                                              const int* __restrict__ csr,
                                              const int* __restrict__ row_start,
                                              const int* __restrict__ deg,
                                              const float* __restrict__ b2,
                                              void* __restrict__ out,
                                              const int* __restrict__ flags, int N) {
  int node = blockIdx.x * 4 + (threadIdx.x >> 6);
  if (node >= N) return;
  int l = threadIdx.x & 63;
  int sub = l & 7;
  int e4 = l >> 4, c4 = l & 15;
  int node_u = rfl(node);
  int st = rfl(row_start[node_u]);
  int cnt = rfl(deg[node_u]);
  const int* cp = csr + st;
  const uint2* h2p = (const uint2*)h2b;
  float ad = ad_[node_u];
  float sp = 0.f, a0 = 0.f, a1 = 0.f, a2 = 0.f, a3 = 0.f;
  int j = 0;
  for (; j + 8 <= cnt; j += 8) {
    int ssub = cp[j + sub];
    float e = as_[ssub] + ad;
    e = fmaxf(e, 0.2f * e);
    float p = __expf(e);
    if (l < 8) sp += p;
#pragma unroll
    for (int pass = 0; pass < 2; pass++) {
      int sa = cp[j + 4 * pass], sb = cp[j + 4 * pass + 1];
      int sc = cp[j + 4 * pass + 2], sd = cp[j + 4 * pass + 3];
      int sk = (e4 == 0) ? sa : (e4 == 1) ? sb : (e4 == 2) ? sc : sd;
      float pk = __shfl(p, 4 * pass + e4);
      uint2 hv = h2p[(size_t)sk * 16 + c4];
      a0 = fmaf(pk, bflo(hv.x), a0); a1 = fmaf(pk, bfhi(hv.x), a1);
      a2 = fmaf(pk, bflo(hv.y), a2); a3 = fmaf(pk, bfhi(hv.y), a3);
    }
  }
  for (; j <= cnt; j++) {  // tail + self-loop
    int s0 = (j < cnt) ? rfl(cp[j]) : node_u;
    float e = as_[s0] + ad;
    e = fmaxf(e, 0.2f * e);
    float p = __expf(e);
    if (l == 0) sp += p;
    float pk = __shfl(p, 0);
    if (e4 == 0) {
      uint2 hv = h2p[(size_t)s0 * 16 + c4];
      a0 = fmaf(pk, bflo(hv.x), a0); a1 = fmaf(pk, bfhi(hv.x), a1);
      a2 = fmaf(pk, bflo(hv.y), a2); a3 = fmaf(pk, bfhi(hv.y), a3);
    }
  }
  sp += __shfl_xor(sp, 1);
  sp += __shfl_xor(sp, 2);
  sp += __shfl_xor(sp, 4);
  float inv = 1.f / (__shfl(sp, 0) + 1e-16f);
  a0 += __shfl_xor(a0, 16); a1 += __shfl_xor(a1, 16);
  a2 += __shfl_xor(a2, 16); a3 += __shfl_xor(a3, 16);
  a0 += __shfl_xor(a0, 32); a1 += __shfl_xor(a1, 32);
  a2 += __shfl_xor(a2, 32); a3 += __shfl_xor(a3, 32);
  if (e4 == 0) {
    int c0 = c4 * 4;
    float r0 = fmaf(a0, inv, b2[c0]);
    float r1 = fmaf(a1, inv, b2[c0 + 1]);
    float r2 = fmaf(a2, inv, b2[c0 + 2]);
    float r3 = fmaf(a3, inv, b2[c0 + 3]);
    if (flags[0]) {
      ((float4*)out)[(size_t)node_u * 16 + c4] = make_float4(r0, r1, r2, r3);
    } else {
      ((uint2*)out)[(size_t)node_u * 16 + c4] = make_uint2(pack2(r0, r1), pack2(r2, r3));
    }
  }
}

extern "C" void kernel_launch(void* const* d_in, const int* in_sizes, int n_in,
                              void* d_out, int out_size, void* d_ws, size_t ws_size,
                              hipStream_t stream) {
  const void* x   = d_in[0];
  const int*  ei  = (const int*)d_in[1];
  const void* W1  = d_in[2];
  const void* a1s = d_in[3];
  const void* a1d = d_in[4];
  const void* b1  = d_in[5];
  const void* gam = d_in[6];
  const void* bet = d_in[7];
  const void* W2  = d_in[8];
  const void* a2s = d_in[9];
  const void* a2d = d_in[10];
  const void* b2  = d_in[11];

  char* ws = (char*)d_ws;
  size_t off = 0;
  auto alloc = [&](size_t bytes) -> void* {
    void* p = ws + off;
    off += (bytes + 255) & ~(size_t)255;
    return p;
  };
  int* flags = (int*)alloc(256);
  // zero region: totals[196] pad 1024 | gsum[128] | gsq[128]
  char* zreg = (char*)alloc(2048);
  int* totals = (int*)zreg;
  float* gsum = (float*)(zreg + 1024);
  float* gsq  = gsum + 128;
  int* H  = (int*)alloc((size_t)NBK * NBLK * 4);
  int* P  = (int*)alloc((size_t)NBK * NBLK * 4);
  u32* ebuf = (u32*)alloc((size_t)N_EDGES * 4);
  int* csr = (int*)alloc((size_t)N_EDGES * 4);
  int* row_start = (int*)alloc((size_t)N_NODES * 4);
  int* deg = (int*)alloc((size_t)N_NODES * 4);
  float* smallf = (float*)alloc(832 * 4);
  float* a1sf = smallf;        float* a1df = smallf + 128;
  float* b1f  = smallf + 256;  float* gamf = smallf + 384;
  float* betf = smallf + 512;  float* a2sf = smallf + 640;
  float* a2df = smallf + 704;  float* b2f  = smallf + 768;
  u16* w1t = (u16*)alloc(16384 * 2);
  u16* w2t = (u16*)alloc(8192 * 2);
  u16* h1b  = (u16*)alloc((size_t)N_NODES * 128 * 2);
  u16* h1ob = (u16*)alloc((size_t)N_NODES * 128 * 2);
  u16* h2b  = (u16*)alloc((size_t)N_NODES * 64 * 2);
  float* al1s = (float*)alloc((size_t)N_NODES * 8 * 4);
  float* al1d = (float*)alloc((size_t)N_NODES * 8 * 4);
  float* al2s = (float*)alloc((size_t)N_NODES * 4);
  float* al2d = (float*)alloc((size_t)N_NODES * 4);
  if (off > ws_size) return;

  hipMemsetAsync(zreg, 0, 2048, stream);
  k_detect<<<1, 256, 0, stream>>>((const u16*)x, (const u32*)ei, flags);
  k_convsmall<<<100, 256, 0, stream>>>(a1s, a1d, b1, gam, bet, a2s, a2d, b2, W1, W2,
                                       smallf, w1t, w2t, flags);

  // ---- CSR build ----
  k_hist<<<NBLK, 256, 0, stream>>>(ei, H, totals, flags);
  k_scan_blk<<<NBK, 256, 0, stream>>>(H, totals, P);
  k_bucket<<<NBLK, 256, 0, stream>>>(ei, P, ebuf, flags);
  k_csr<<<NBK, 256, 0, stream>>>(ebuf, totals, row_start, deg, csr, N_NODES);

  // ---- layer 1 (alpha1 fused into GEMM epilogue) ----
  k_gemm_mfma<128, false, true, true><<<(N_NODES + 63) / 64, 256, 0, stream>>>(
      x, w1t, nullptr, nullptr, nullptr, nullptr, a1sf, a1df, al1s, al1d,
      h1b, N_NODES, flags);
  k_agg1<<<(N_NODES + 3) / 4, 256, 0, stream>>>(h1b, al1s, al1d, csr, row_start, deg,
                                                b1f, h1ob, N_NODES);
  k_bnstat<<<(N_NODES + 127) / 128, 256, 0, stream>>>(h1ob, gsum, gsq, N_NODES);

  // ---- layer 2 (BN finalize + BN/ELU + alpha2 fused into GEMM) ----
  k_gemm_mfma<64, true, false, false><<<(N_NODES + 63) / 64, 256, 0, stream>>>(
      h1ob, w2t, gsum, gsq, gamf, betf, a2sf, a2df, al2s, al2d,
      h2b, N_NODES, flags);
  k_agg2<<<(N_NODES + 3) / 4, 256, 0, stream>>>(h2b, al2s, al2d, csr, row_start, deg,
                                                b2f, d_out, flags, N_NODES);
}

// Round 10
// 334.237 us; speedup vs baseline: 1.5130x; 1.0701x over previous
//
#include <hip/hip_runtime.h>
#include <hip/hip_bf16.h>

#define N_NODES 50000
#define N_EDGES 1600000
#define HEADS 8
#define NBK 196   // buckets: dst>>8
#define NBLK 196  // edge tiles: 196*8192 >= 1.6M
#define EPB 8192  // edges per bucket-build block

typedef unsigned short u16;
typedef unsigned char u8;
typedef unsigned int u32;
typedef __attribute__((ext_vector_type(8))) short bf16x8;
typedef __attribute__((ext_vector_type(4))) float f32x4;

__device__ __forceinline__ float bf2f(u16 u) {
  union { u32 i; float f; } v; v.i = ((u32)u) << 16; return v.f;
}
__device__ __forceinline__ float bflo(u32 p) {
  union { u32 i; float f; } v; v.i = p << 16; return v.f;
}
__device__ __forceinline__ float bfhi(u32 p) {
  union { u32 i; float f; } v; v.i = p & 0xffff0000u; return v.f;
}
__device__ __forceinline__ u16 f2bf(float f) {
  union { float f; u32 i; } v; v.f = f;
  u32 r = v.i + 0x7fff + ((v.i >> 16) & 1);  // RNE
  return (u16)(r >> 16);
}
__device__ __forceinline__ u32 pack2(float a, float b) {
  return (u32)f2bf(a) | ((u32)f2bf(b) << 16);
}
__device__ __forceinline__ int rfl(int x) { return __builtin_amdgcn_readfirstlane(x); }

// ---------------- dtype auto-detection ----------------
__global__ void k_detect(const u16* __restrict__ x, const u32* __restrict__ ei,
                         int* __restrict__ flags) {
  __shared__ int cbig, cnz;
  if (threadIdx.x == 0) { cbig = 0; cnz = 0; }
  __syncthreads();
  int lb = 0, ln = 0;
  for (int i = threadIdx.x; i < 4096; i += 256) {
    int ex = (x[i] >> 7) & 0xff;
    lb += (ex >= 140);
    if (i < 2048) ln += (ei[2 * i + 1] != 0);
  }
  atomicAdd(&cbig, lb); atomicAdd(&cnz, ln);
  __syncthreads();
  if (threadIdx.x == 0) {
    flags[0] = (cbig > 16) ? 1 : 0;   // 1: floats are fp32
    flags[1] = (cnz == 0) ? 1 : 0;    // 1: edge_index is int64
  }
}

// ---------------- converter: vectors -> fp32, W1/W2 -> transposed bf16 -------
__global__ void k_convsmall(const void* a1s, const void* a1d, const void* b1,
                            const void* gam, const void* bet, const void* a2s,
                            const void* a2d, const void* b2, const void* W1,
                            const void* W2, float* __restrict__ smallf,
                            u16* __restrict__ w1t, u16* __restrict__ w2t,
                            const int* __restrict__ flags) {
  int i = blockIdx.x * 256 + threadIdx.x;
  if (i >= 25408) return;
  bool f32 = flags[0] != 0;
  auto ld = [&](const void* p, int off) -> float {
    return f32 ? ((const float*)p)[off] : bf2f(((const u16*)p)[off]);
  };
  if (i >= 17216) {            // W2T[n][k], n<64, k<128  <- W2[k*64+n]
    int j = i - 17216, n = j >> 7, k = j & 127;
    w2t[j] = f2bf(ld(W2, k * 64 + n));
  } else if (i >= 832) {       // W1T[n][k], n<128, k<128 <- W1[k*128+n]
    int j = i - 832, n = j >> 7, k = j & 127;
    w1t[j] = f2bf(ld(W1, k * 128 + n));
  } else {
    const void* src; int off;
    if (i >= 768)      { src = b2;  off = i - 768; }
    else if (i >= 704) { src = a2d; off = i - 704; }
    else if (i >= 640) { src = a2s; off = i - 640; }
    else if (i >= 512) { src = bet; off = i - 512; }
    else if (i >= 384) { src = gam; off = i - 384; }
    else if (i >= 256) { src = b1;  off = i - 256; }
    else if (i >= 128) { src = a1d; off = i - 128; }
    else               { src = a1s; off = i; }
    smallf[i] = ld(src, off);
  }
}

// ---------------- CSR build (atomic-free two-level counting sort) ----------
__global__ __launch_bounds__(256) void k_hist(const int* __restrict__ ei,
                                              int* __restrict__ H,
                                              int* __restrict__ totals,
                                              const int* __restrict__ flags) {
  __shared__ int hist[NBK];
  int t = threadIdx.x, blk = blockIdx.x;
  for (int i = t; i < NBK; i += 256) hist[i] = 0;
  __syncthreads();
  bool i64 = flags[1] != 0;
  int base = blk * EPB;
  for (int k = 0; k < 32; k++) {
    int e = base + k * 256 + t;
    if (e < N_EDGES) {
      int d = i64 ? ei[2 * (N_EDGES + e)] : ei[N_EDGES + e];
      atomicAdd(&hist[d >> 8], 1);
    }
  }
  __syncthreads();
  for (int i = t; i < NBK; i += 256) {
    H[i * NBLK + blk] = hist[i];
    atomicAdd(&totals[i], hist[i]);
  }
}

// per-bucket scan over blocks; bucket bases computed inline from totals
__global__ void k_scan_blk(const int* __restrict__ H, const int* __restrict__ totals,
                           int* __restrict__ P) {
  __shared__ int tb[256], tmp[256];
  int t = threadIdx.x, b = blockIdx.x;
  int v0 = (t < NBK) ? totals[t] : 0;
  tb[t] = v0; __syncthreads();
  for (int o = 1; o < 256; o <<= 1) {
    int x = (t >= o) ? tb[t - o] : 0; __syncthreads();
    tb[t] += x; __syncthreads();
  }
  int base = (b == 0) ? 0 : tb[b - 1];
  int v = (t < NBLK) ? H[b * NBLK + t] : 0;
  tmp[t] = v; __syncthreads();
  for (int o = 1; o < 256; o <<= 1) {
    int x = (t >= o) ? tmp[t - o] : 0; __syncthreads();
    tmp[t] += x; __syncthreads();
  }
  if (t < NBLK) P[b * NBLK + t] = base + tmp[t] - v;
}

// LDS counting sort per 8192-edge tile, coalesced global writes.
__global__ __launch_bounds__(256) void k_bucket(const int* __restrict__ ei,
                                                const int* __restrict__ P,
                                                u32* __restrict__ buf,
                                                const int* __restrict__ flags) {
  __shared__ u32 sv[EPB];
  __shared__ u16 rank[EPB];
  __shared__ u8  sk8[EPB];
  __shared__ int cnt[NBK], scn[NBK], tmp[256];
  int t = threadIdx.x, blk = blockIdx.x;
  int base = blk * EPB;
  int nE = N_EDGES - base; if (nE > EPB) nE = EPB;
  for (int i = t; i < NBK; i += 256) cnt[i] = 0;
  __syncthreads();
  bool i64 = flags[1] != 0;
  for (int k = 0; k < EPB / 256; k++) {
    int li = k * 256 + t, e = base + li;
    if (li < nE) {
      int d = i64 ? ei[2 * (N_EDGES + e)] : ei[N_EDGES + e];
      rank[li] = (u16)atomicAdd(&cnt[d >> 8], 1);
    }
  }
  __syncthreads();
  int v = (t < NBK) ? cnt[t] : 0;
  tmp[t] = v; __syncthreads();
  for (int o = 1; o < 256; o <<= 1) {
    int x = (t >= o) ? tmp[t - o] : 0; __syncthreads();
    tmp[t] += x; __syncthreads();
  }
  if (t < NBK) scn[t] = tmp[t] - v;
  __syncthreads();
  for (int k = 0; k < EPB / 256; k++) {
    int li = k * 256 + t, e = base + li;
    if (li < nE) {
      int s = i64 ? ei[2 * e] : ei[e];
      int d = i64 ? ei[2 * (N_EDGES + e)] : ei[N_EDGES + e];
      int key = d >> 8;
      int pos = scn[key] + rank[li];
      sv[pos] = ((u32)(d & 255) << 16) | (u32)s;
      sk8[pos] = (u8)key;
    }
  }
  __syncthreads();
  for (int i = t; i < nE; i += 256) {
    int b = sk8[i];
    buf[P[b * NBLK + blk] + (i - scn[b])] = sv[i];
  }
}

__global__ __launch_bounds__(256) void k_csr(const u32* __restrict__ buf,
                                             const int* __restrict__ totals,
                                             int* __restrict__ row_start,
                                             int* __restrict__ deg,
                                             int* __restrict__ csr, int N) {
  __shared__ int tb[256], cnt[256], scn[256], cur[256];
  int b = blockIdx.x, t = threadIdx.x;
  int v0 = (t < NBK) ? totals[t] : 0;
  tb[t] = v0; __syncthreads();
  for (int o = 1; o < 256; o <<= 1) {
    int x = (t >= o) ? tb[t - o] : 0; __syncthreads();
    tb[t] += x; __syncthreads();
  }
  int lo = (b == 0) ? 0 : tb[b - 1];
  int hi = tb[b];
  cnt[t] = 0; __syncthreads();
  for (int e = lo + t; e < hi; e += 256) atomicAdd(&cnt[(buf[e] >> 16) & 255], 1);
  __syncthreads();
  int v = cnt[t];
  scn[t] = v; __syncthreads();
  for (int o = 1; o < 256; o <<= 1) {
    int x = (t >= o) ? scn[t - o] : 0; __syncthreads();
    scn[t] += x; __syncthreads();
  }
  int excl = scn[t] - v;
  int node = b * 256 + t;
  if (node < N) { row_start[node] = lo + excl; deg[node] = v; }
  cur[t] = lo + excl;
  __syncthreads();
  for (int e = lo + t; e < hi; e += 256) {
    u32 p = buf[e];
    int pos = atomicAdd(&cur[(p >> 16) & 255], 1);
    csr[pos] = p & 0xffff;
  }
}

// ---------------- MFMA GEMM: A[M,128] x BT[NCOLS,128] -> bf16 C row-major ---
// ALPHA1 (layer1): per-head (=per-nt) dots -> as_out/ad_out [row*8+nt]
// EPI (layer2): BN finalize (from gsum/gsq) + BN+ELU on A-load; alpha2 dots.
template <int NCOLS, bool EPI, bool ALPHA1, bool AFLAG>
__global__ __launch_bounds__(256) void k_gemm_mfma(const void* __restrict__ A,
                                                   const u16* __restrict__ BT,
                                                   const float* __restrict__ bnsum,
                                                   const float* __restrict__ bnsq,
                                                   const float* __restrict__ gamma,
                                                   const float* __restrict__ beta,
                                                   const float* __restrict__ va,
                                                   const float* __restrict__ vb,
                                                   float* __restrict__ as_out,
                                                   float* __restrict__ ad_out,
                                                   u16* __restrict__ C, int M,
                                                   const int* __restrict__ flags) {
  constexpr int KP = 136;
  constexpr int NT = NCOLS / 16;
  __shared__ u16 As[64 * KP];
  __shared__ u16 Bs[NCOLS * KP];
  __shared__ float sSc[128], sSh[128];
  int t = threadIdx.x;
  int row0 = blockIdx.x * 64;
  bool af32 = AFLAG ? (flags[0] != 0) : false;

  if (EPI) {  // inline BN finalize (redundant per block, trivial cost)
    if (t < 128) {
      float mu = bnsum[t] * (1.f / (float)N_NODES);
      float var = fmaxf(bnsq[t] * (1.f / (float)N_NODES) - mu * mu, 0.f);
      float sc = gamma[t] * rsqrtf(var + 1e-5f);
      sSc[t] = sc; sSh[t] = beta[t] - mu * sc;
    }
    __syncthreads();
  }

  for (int i = t; i < NCOLS * 16; i += 256) {
    int n = i >> 4, q = i & 15;
    *(uint4*)&Bs[n * KP + q * 8] = ((const uint4*)BT)[n * 16 + q];
  }
  for (int i = t; i < 64 * 32; i += 256) {
    int r = i >> 5, c4 = i & 31;
    int row = row0 + r;
    uint2 pk = make_uint2(0u, 0u);
    if (row < M) {
      if (EPI) {
        uint2 p = ((const uint2*)A)[(size_t)row * 32 + c4];
        int c = c4 * 4;
        float v0 = bflo(p.x), v1 = bfhi(p.x), v2 = bflo(p.y), v3 = bfhi(p.y);
        v0 = fmaf(v0, sSc[c],     sSh[c]);     v0 = v0 > 0.f ? v0 : __expf(v0) - 1.f;
        v1 = fmaf(v1, sSc[c + 1], sSh[c + 1]); v1 = v1 > 0.f ? v1 : __expf(v1) - 1.f;
        v2 = fmaf(v2, sSc[c + 2], sSh[c + 2]); v2 = v2 > 0.f ? v2 : __expf(v2) - 1.f;
        v3 = fmaf(v3, sSc[c + 3], sSh[c + 3]); v3 = v3 > 0.f ? v3 : __expf(v3) - 1.f;
        pk.x = pack2(v0, v1); pk.y = pack2(v2, v3);
      } else if (af32) {
        float4 v = ((const float4*)A)[(size_t)row * 32 + c4];
        pk.x = pack2(v.x, v.y); pk.y = pack2(v.z, v.w);
      } else {
        pk = ((const uint2*)A)[(size_t)row * 32 + c4];
      }
    }
    *(uint2*)&As[r * KP + c4 * 4] = pk;
  }
  __syncthreads();

  int lane = t & 63, w = t >> 6;
  int m = lane & 15, quad = lane >> 4;
  f32x4 acc[NT];
#pragma unroll
  for (int nt = 0; nt < NT; nt++) acc[nt] = (f32x4)(0.f);
  const u16* aBase = &As[(w * 16 + m) * KP + quad * 8];
  const u16* bBase = &Bs[m * KP + quad * 8];
#pragma unroll
  for (int ks = 0; ks < 4; ks++) {
    bf16x8 af = *(const bf16x8*)(aBase + ks * 32);
#pragma unroll
    for (int nt = 0; nt < NT; nt++) {
      bf16x8 bf = *(const bf16x8*)(bBase + nt * 16 * KP + ks * 32);
      acc[nt] = __builtin_amdgcn_mfma_f32_16x16x32_bf16(af, bf, acc[nt], 0, 0, 0);
    }
  }
  int orow0 = row0 + w * 16 + quad * 4;
#pragma unroll
  for (int nt = 0; nt < NT; nt++) {
#pragma unroll
    for (int r = 0; r < 4; r++) {
      int row = orow0 + r;
      if (row < M) C[(size_t)row * NCOLS + nt * 16 + m] = f2bf(acc[nt][r]);
    }
  }
  if (ALPHA1) {
    float pav[NT], pbv[NT];
#pragma unroll
    for (int nt = 0; nt < NT; nt++) { pav[nt] = va[nt * 16 + m]; pbv[nt] = vb[nt * 16 + m]; }
#pragma unroll
    for (int r = 0; r < 4; r++) {
      int row = orow0 + r;
#pragma unroll
      for (int nt = 0; nt < NT; nt++) {
        float vs = acc[nt][r] * pav[nt];
        float vd = acc[nt][r] * pbv[nt];
        vs += __shfl_xor(vs, 1); vd += __shfl_xor(vd, 1);
        vs += __shfl_xor(vs, 2); vd += __shfl_xor(vd, 2);
        vs += __shfl_xor(vs, 4); vd += __shfl_xor(vd, 4);
        vs += __shfl_xor(vs, 8); vd += __shfl_xor(vd, 8);
        if (row < M && m == 0) { as_out[row * 8 + nt] = vs; ad_out[row * 8 + nt] = vd; }
      }
    }
  }
  if (EPI) {
    float pav[NT], pbv[NT];
#pragma unroll
    for (int nt = 0; nt < NT; nt++) { pav[nt] = va[nt * 16 + m]; pbv[nt] = vb[nt * 16 + m]; }
#pragma unroll
    for (int r = 0; r < 4; r++) {
      float vs = 0.f, vd = 0.f;
#pragma unroll
      for (int nt = 0; nt < NT; nt++) {
        vs = fmaf(acc[nt][r], pav[nt], vs);
        vd = fmaf(acc[nt][r], pbv[nt], vd);
      }
      vs += __shfl_xor(vs, 1); vd += __shfl_xor(vd, 1);
      vs += __shfl_xor(vs, 2); vd += __shfl_xor(vd, 2);
      vs += __shfl_xor(vs, 4); vd += __shfl_xor(vd, 4);
      vs += __shfl_xor(vs, 8); vd += __shfl_xor(vd, 8);
      int row = orow0 + r;
      if (row < M && m == 0) { as_out[row] = vs; ad_out[row] = vd; }
    }
  }
}

// ---------------- aggregation layer 1: round-6 proven structure -------------
// shared-exp unroll 8: lane (head=l>>3, sub=l&7) computes exp for (edge=sub,
// head); p distributed within the aligned 8-lane head group via shfl.
__global__ __launch_bounds__(256) void k_agg1(const u16* __restrict__ h1b,
                                              const float* __restrict__ as_,
                                              const float* __restrict__ ad_,
                                              const int* __restrict__ csr,
                                              const int* __restrict__ row_start,
                                              const int* __restrict__ deg,
                                              const float* __restrict__ b1,
                                              u16* __restrict__ out, int N) {
  int node = blockIdx.x * 4 + (threadIdx.x >> 6);
  if (node >= N) return;
  int l = threadIdx.x & 63;
  int head = l >> 3, sub = l & 7;
  int gbase = l & 56;  // base lane of this head group
  int node_u = rfl(node);
  int st = rfl(row_start[node_u]);
  int cnt = rfl(deg[node_u]);
  const int* cp = csr + st;
  const u32* h32 = (const u32*)h1b;
  float ad = ad_[(node_u << 3) | head];
  float sp = 0.f, a0 = 0.f, a1 = 0.f;
  int j = 0;
  for (; j + 8 <= cnt; j += 8) {
    int ssub = cp[j + sub];                       // per-lane: my slot's src
    float e = as_[(ssub << 3) | head] + ad;
    e = fmaxf(e, 0.2f * e);
    float p = __expf(e);
    sp += p;                                      // per-lane partial of s
#pragma unroll
    for (int k = 0; k < 8; k++) {
      int sk = cp[j + k];                         // uniform -> s_load
      float pk = __shfl(p, gbase | k);
      u32 hv = h32[(sk << 6) | l];
      a0 = fmaf(pk, bflo(hv), a0);
      a1 = fmaf(pk, bfhi(hv), a1);
    }
  }
  for (; j < cnt; j++) {
    int s0 = cp[j];
    float e0 = as_[(s0 << 3) | head] + ad;
    e0 = fmaxf(e0, 0.2f * e0);
    float p0 = __expf(e0);
    if (sub == 0) sp += p0;
    u32 hv = h32[(s0 << 6) | l];
    a0 = fmaf(p0, bflo(hv), a0); a1 = fmaf(p0, bfhi(hv), a1);
  }
  { // self-loop
    float e0 = as_[(node_u << 3) | head] + ad;
    e0 = fmaxf(e0, 0.2f * e0);
    float p0 = __expf(e0);
    if (sub == 0) sp += p0;
    u32 hv = h32[((size_t)node_u << 6) | l];
    a0 = fmaf(p0, bflo(hv), a0); a1 = fmaf(p0, bfhi(hv), a1);
  }
  sp += __shfl_xor(sp, 1);
  sp += __shfl_xor(sp, 2);
  sp += __shfl_xor(sp, 4);
  float inv = 1.f / (sp + 1e-16f);
  int c0 = l * 2;
  ((u32*)out)[((size_t)node_u << 6) + l] =
      pack2(fmaf(a0, inv, b1[c0]), fmaf(a1, inv, b1[c0 + 1]));
}

// ---------------- batch norm stats ----------------
__global__ void k_bnstat(const u16* __restrict__ h, float* __restrict__ gsum,
                         float* __restrict__ gsq, int N) {
  __shared__ float ts[256], tq[256];
  int t = threadIdx.x, col = t & 127, rr = t >> 7;
  int row0 = blockIdx.x * 128;
  float s = 0.f, q = 0.f;
  for (int r = rr; r < 128; r += 2) {
    int row = row0 + r;
    if (row < N) {
      float v = bf2f(h[((size_t)row << 7) + col]);
      s += v; q = fmaf(v, v, q);
    }
  }
  ts[t] = s; tq[t] = q; __syncthreads();
  if (t < 128) {
    atomicAdd(&gsum[t], ts[t] + ts[t + 128]);
    atomicAdd(&gsq[t], tq[t] + tq[t + 128]);
  }
}

// ---------------- aggregation layer 2 -> output (round-6 proven) ------------
__global__ __launch_bounds__(256) void k_agg2(const u16* __restrict__ h2b,
                                              const float* __restrict__ as_,
                                              const float* __restrict__ ad_,
                                              const int* __restrict__ csr,
                                              const int* __restrict__ row_start,
                                              const int* __restrict__ deg,
                                              const float* __restrict__ b2,
                                              void* __restrict__ out,
                                              const int* __restrict__ flags, int N) {
  int node = blockIdx.x * 4 + (threadIdx.x >> 6);
  if (node >= N) return;
  int l = threadIdx.x & 63;
  int sub = l & 7, gbase = l & 56;
  int node_u = rfl(node);
  int st = rfl(row_start[node_u]);
  int cnt = rfl(deg[node_u]);
  const int* cp = csr + st;
  float ad = ad_[node_u];
  float sp = 0.f, a = 0.f;
  int j = 0;
  for (; j + 8 <= cnt; j += 8) {
    int ssub = cp[j + sub];
    float e = as_[ssub] + ad;
    e = fmaxf(e, 0.2f * e);
    float p = __expf(e);
    sp += p;
#pragma unroll
    for (int k = 0; k < 8; k++) {
      int sk = cp[j + k];                         // uniform -> s_load
      float pk = __shfl(p, gbase | k);
      a = fmaf(pk, bf2f((h2b + (sk << 6))[l]), a);
    }
  }
  for (; j < cnt; j++) {
    int s0 = cp[j];
    float e0 = as_[s0] + ad;
    e0 = fmaxf(e0, 0.2f * e0);
    float p0 = __expf(e0);
    if (sub == 0) sp += p0;
    a = fmaf(p0, bf2f((h2b + (s0 << 6))[l]), a);
  }
  { // self-loop
    float e0 = as_[node_u] + ad;
    e0 = fmaxf(e0, 0.2f * e0);
    float p0 = __expf(e0);
    if (sub == 0) sp += p0;
    a = fmaf(p0, bf2f((h2b + (node_u << 6))[l]), a);
  }
  sp += __shfl_xor(sp, 1);
  sp += __shfl_xor(sp, 2);
  sp += __shfl_xor(sp, 4);
  float r = a / (sp + 1e-16f) + b2[l];
  size_t idx = ((size_t)node_u << 6) + l;
  if (flags[0]) ((float*)out)[idx] = r;
  else          ((u16*)out)[idx] = f2bf(r);
}

extern "C" void kernel_launch(void* const* d_in, const int* in_sizes, int n_in,
                              void* d_out, int out_size, void* d_ws, size_t ws_size,
                              hipStream_t stream) {
  const void* x   = d_in[0];
  const int*  ei  = (const int*)d_in[1];
  const void* W1  = d_in[2];
  const void* a1s = d_in[3];
  const void* a1d = d_in[4];
  const void* b1  = d_in[5];
  const void* gam = d_in[6];
  const void* bet = d_in[7];
  const void* W2  = d_in[8];
  const void* a2s = d_in[9];
  const void* a2d = d_in[10];
  const void* b2  = d_in[11];

  char* ws = (char*)d_ws;
  size_t off = 0;
  auto alloc = [&](size_t bytes) -> void* {
    void* p = ws + off;
    off += (bytes + 255) & ~(size_t)255;
    return p;
  };
  int* flags = (int*)alloc(256);
  // zero region: totals[196] pad 1024 | gsum[128] | gsq[128]
  char* zreg = (char*)alloc(2048);
  int* totals = (int*)zreg;
  float* gsum = (float*)(zreg + 1024);
  float* gsq  = gsum + 128;
  int* H  = (int*)alloc((size_t)NBK * NBLK * 4);
  int* P  = (int*)alloc((size_t)NBK * NBLK * 4);
  u32* ebuf = (u32*)alloc((size_t)N_EDGES * 4);
  int* csr = (int*)alloc((size_t)N_EDGES * 4);
  int* row_start = (int*)alloc((size_t)N_NODES * 4);
  int* deg = (int*)alloc((size_t)N_NODES * 4);
  float* smallf = (float*)alloc(832 * 4);
  float* a1sf = smallf;        float* a1df = smallf + 128;
  float* b1f  = smallf + 256;  float* gamf = smallf + 384;
  float* betf = smallf + 512;  float* a2sf = smallf + 640;
  float* a2df = smallf + 704;  float* b2f  = smallf + 768;
  u16* w1t = (u16*)alloc(16384 * 2);
  u16* w2t = (u16*)alloc(8192 * 2);
  u16* h1b  = (u16*)alloc((size_t)N_NODES * 128 * 2);
  u16* h1ob = (u16*)alloc((size_t)N_NODES * 128 * 2);
  u16* h2b  = (u16*)alloc((size_t)N_NODES * 64 * 2);
  float* al1s = (float*)alloc((size_t)N_NODES * 8 * 4);
  float* al1d = (float*)alloc((size_t)N_NODES * 8 * 4);
  float* al2s = (float*)alloc((size_t)N_NODES * 4);
  float* al2d = (float*)alloc((size_t)N_NODES * 4);
  if (off > ws_size) return;

  hipMemsetAsync(zreg, 0, 2048, stream);
  k_detect<<<1, 256, 0, stream>>>((const u16*)x, (const u32*)ei, flags);
  k_convsmall<<<100, 256, 0, stream>>>(a1s, a1d, b1, gam, bet, a2s, a2d, b2, W1, W2,
                                       smallf, w1t, w2t, flags);

  // ---- CSR build ----
  k_hist<<<NBLK, 256, 0, stream>>>(ei, H, totals, flags);
  k_scan_blk<<<NBK, 256, 0, stream>>>(H, totals, P);
  k_bucket<<<NBLK, 256, 0, stream>>>(ei, P, ebuf, flags);
  k_csr<<<NBK, 256, 0, stream>>>(ebuf, totals, row_start, deg, csr, N_NODES);

  // ---- layer 1 (alpha1 fused into GEMM epilogue) ----
  k_gemm_mfma<128, false, true, true><<<(N_NODES + 63) / 64, 256, 0, stream>>>(
      x, w1t, nullptr, nullptr, nullptr, nullptr, a1sf, a1df, al1s, al1d,
      h1b, N_NODES, flags);
  k_agg1<<<(N_NODES + 3) / 4, 256, 0, stream>>>(h1b, al1s, al1d, csr, row_start, deg,
                                                b1f, h1ob, N_NODES);
  k_bnstat<<<(N_NODES + 127) / 128, 256, 0, stream>>>(h1ob, gsum, gsq, N_NODES);

  // ---- layer 2 (BN finalize + BN/ELU + alpha2 fused into GEMM) ----
  k_gemm_mfma<64, true, false, false><<<(N_NODES + 63) / 64, 256, 0, stream>>>(
      h1ob, w2t, gsum, gsq, gamf, betf, a2sf, a2df, al2s, al2d,
      h2b, N_NODES, flags);
  k_agg2<<<(N_NODES + 3) / 4, 256, 0, stream>>>(h2b, al2s, al2d, csr, row_start, deg,
                                                b2f, d_out, flags, N_NODES);
}